// Round 3
// baseline (1260.018 us; speedup 1.0000x reference)
//
#include <hip/hip_runtime.h>

// ---------------------------------------------------------------------------
// GCN link prediction, bucketed-scatter + LDS-accumulate formulation.
//   Bucket edges by dst>>7 (128 nodes/bucket, 782 buckets) — only ~782 write
//   frontiers so L2 merges scatter writes (vs 100k frontiers thrashing).
//   Aggregation: one block per bucket, LDS fp32 accumulator (ds_add_f32),
//   gathers prescaled rows. Layer-2 GEMM (32->16) fused into b1 epilogue.
// ---------------------------------------------------------------------------

#define NPB 128        // nodes per bucket
#define NBMAX 1024     // supports n <= 131072
#define A3_CHUNK 4096  // edges per scatter block (256 thr x 16)

__global__ void k_zero(int* __restrict__ p, int n) {
    int i = blockIdx.x * blockDim.x + threadIdx.x;
    if (i < n) p[i] = 0;
}

// Bucket histogram: LDS-privatized, ~NB global atomics per block.
__global__ __launch_bounds__(256) void k_a1(const int* __restrict__ dst,
                                            int* __restrict__ bcnt, int E, int NB) {
    __shared__ int lb[NBMAX];
    int t = threadIdx.x;
    for (int i = t; i < NB; i += 256) lb[i] = 0;
    __syncthreads();
    for (int e = blockIdx.x * 256 + t; e < E; e += gridDim.x * 256)
        atomicAdd(&lb[dst[e] >> 7], 1);
    __syncthreads();
    for (int i = t; i < NB; i += 256) {
        int c = lb[i];
        if (c) atomicAdd(&bcnt[i], c);
    }
}

// Single-block exclusive scan of bucket counts -> bbase, bcursor. NB <= 1024.
__global__ __launch_bounds__(256) void k_scanb(const int* __restrict__ bcnt,
                                               int* __restrict__ bbase,
                                               int* __restrict__ bcursor, int NB) {
    __shared__ int sh[256];
    int t = threadIdx.x;
    int i0 = t * 4;
    int v0 = (i0 + 0 < NB) ? bcnt[i0 + 0] : 0;
    int v1 = (i0 + 1 < NB) ? bcnt[i0 + 1] : 0;
    int v2 = (i0 + 2 < NB) ? bcnt[i0 + 2] : 0;
    int v3 = (i0 + 3 < NB) ? bcnt[i0 + 3] : 0;
    sh[t] = v0 + v1 + v2 + v3;
    __syncthreads();
    for (int off = 1; off < 256; off <<= 1) {
        int add = (t >= off) ? sh[t - off] : 0;
        __syncthreads();
        sh[t] += add;
        __syncthreads();
    }
    int run = (t > 0) ? sh[t - 1] : 0;
    if (i0 + 0 < NB) { bbase[i0 + 0] = run; bcursor[i0 + 0] = run; } run += v0;
    if (i0 + 1 < NB) { bbase[i0 + 1] = run; bcursor[i0 + 1] = run; } run += v1;
    if (i0 + 2 < NB) { bbase[i0 + 2] = run; bcursor[i0 + 2] = run; } run += v2;
    if (i0 + 3 < NB) { bbase[i0 + 3] = run; bcursor[i0 + 3] = run; }
    if (t == 255) bbase[NB] = sh[255];
}

// Bucketed scatter: per-block LDS hist -> one global cursor add per
// (block,bucket) -> LDS-ranked positions. ~782 hot frontiers, L2 merges.
__global__ __launch_bounds__(256) void k_a3(const int* __restrict__ src,
                                            const int* __restrict__ dst,
                                            int* __restrict__ bcursor,
                                            int2* __restrict__ eb, int E, int NB) {
    __shared__ int lhist[NBMAX];
    __shared__ int lbase[NBMAX];
    int t = threadIdx.x;
    int e0 = blockIdx.x * A3_CHUNK;
    for (int i = t; i < NB; i += 256) lhist[i] = 0;
    __syncthreads();
    int mys[16], myd[16];
#pragma unroll
    for (int j = 0; j < 16; ++j) {
        int e = e0 + j * 256 + t;  // coalesced
        if (e < E) {
            mys[j] = src[e];
            myd[j] = dst[e];
            atomicAdd(&lhist[myd[j] >> 7], 1);
        } else {
            myd[j] = -1;
        }
    }
    __syncthreads();
    for (int i = t; i < NB; i += 256) {
        int c = lhist[i];
        lbase[i] = c ? atomicAdd(&bcursor[i], c) : 0;
        lhist[i] = 0;
    }
    __syncthreads();
#pragma unroll
    for (int j = 0; j < 16; ++j) {
        if (myd[j] >= 0) {
            int b = myd[j] >> 7;
            int r = atomicAdd(&lhist[b], 1);
            eb[lbase[b] + r] = make_int2(mys[j], myd[j]);
        }
    }
}

// Per-bucket degree count from bucketed edges -> inv_sqrt(deg+1). No global atomics.
__global__ __launch_bounds__(256) void k_deginv(const int* __restrict__ bbase,
                                                const int2* __restrict__ eb,
                                                float* __restrict__ inv, int n) {
    __shared__ int cnt[NPB];
    int t = threadIdx.x, b = blockIdx.x;
    int nbase = b * NPB;
    if (t < NPB) cnt[t] = 0;
    __syncthreads();
    int beg = bbase[b], end = bbase[b + 1];
    for (int i = beg + t; i < end; i += 256) atomicAdd(&cnt[eb[i].y - nbase], 1);
    __syncthreads();
    if (t < NPB) {
        int node = nbase + t;
        if (node < n) inv[node] = rsqrtf((float)(cnt[t] + 1));
    }
}

// xws[n][32] = (x[n] @ W1) * inv[n]
__global__ __launch_bounds__(256) void k_xw(const float* __restrict__ x,
                                            const float* __restrict__ W1,
                                            const float* __restrict__ inv,
                                            float* __restrict__ xws, int n) {
    __shared__ float W1s[128 * 32];   // 16 KB
    __shared__ float xsh[8 * 128];    // 4 KB
    int t = threadIdx.x;
#pragma unroll
    for (int i = 0; i < 16; ++i) W1s[i * 256 + t] = W1[i * 256 + t];
    int base = blockIdx.x * 8;
    if (base + 8 <= n) {
        ((float4*)xsh)[t] = ((const float4*)(x + (size_t)base * 128))[t];
    } else {
        for (int i = t; i < 8 * 128; i += 256) {
            int node = base + (i >> 7);
            xsh[i] = (node < n) ? x[(size_t)node * 128 + (i & 127)] : 0.0f;
        }
    }
    __syncthreads();
    int j = t & 31, r = t >> 5;
    int node = base + r;
    if (node >= n) return;
    float sum = 0.0f;
#pragma unroll
    for (int k = 0; k < 128; ++k) sum += xsh[r * 128 + k] * W1s[k * 32 + j];
    xws[(size_t)node * 32 + j] = sum * inv[node];
}

// Layer 1 aggregate (LDS acc) + fused relu/bias + fused (h@W2)*inv epilogue.
__global__ __launch_bounds__(512) void k_b1(const int* __restrict__ bbase,
                                            const int2* __restrict__ eb,
                                            const float* __restrict__ xws,
                                            const float* __restrict__ inv,
                                            const float* __restrict__ b1,
                                            const float* __restrict__ W2,
                                            float* __restrict__ hws, int n) {
    __shared__ float acc[NPB * 33];  // stride 33: conflict-free ds_add + epilogue
    __shared__ float W2s[32 * 16];
    __shared__ float b1s[32];
    int t = threadIdx.x, b = blockIdx.x;
    int nbase = b * NPB;
    for (int i = t; i < NPB * 33; i += 512) acc[i] = 0.0f;
    W2s[t] = W2[t];
    if (t < 32) b1s[t] = b1[t];
    __syncthreads();
    int beg = bbase[b], end = bbase[b + 1];
    int col = t & 31, g = t >> 5;  // 16 edge-groups of 32 lanes
    int i = beg + g;
    for (; i + 16 < end; i += 32) {  // unroll 2 for ILP on the gathers
        int2 e0 = eb[i], e1 = eb[i + 16];
        float v0 = xws[(size_t)e0.x * 32 + col];
        float v1 = xws[(size_t)e1.x * 32 + col];
        atomicAdd(&acc[(e0.y - nbase) * 33 + col], v0);
        atomicAdd(&acc[(e1.y - nbase) * 33 + col], v1);
    }
    for (; i < end; i += 16) {
        int2 e = eb[i];
        float v = xws[(size_t)e.x * 32 + col];
        atomicAdd(&acc[(e.y - nbase) * 33 + col], v);
    }
    __syncthreads();
    // finalize h in-place: h = relu(inv[d]*(acc + xws[d]) + b1)
    for (int idx = t; idx < NPB * 32; idx += 512) {
        int nl = idx >> 5, c = idx & 31;
        int node = nbase + nl;
        if (node < n) {
            float tot = acc[nl * 33 + c] + xws[(size_t)node * 32 + c];
            acc[nl * 33 + c] = fmaxf(inv[node] * tot + b1s[c], 0.0f);
        }
    }
    __syncthreads();
    // hws[node][16] = (h_row @ W2) * inv[node]
    for (int idx = t; idx < NPB * 16; idx += 512) {
        int nl = idx >> 4, oc = idx & 15;
        int node = nbase + nl;
        if (node < n) {
            float s = 0.0f;
#pragma unroll
            for (int k = 0; k < 32; ++k) s += acc[nl * 33 + k] * W2s[k * 16 + oc];
            hws[(size_t)node * 16 + oc] = s * inv[node];
        }
    }
}

// Layer 2 aggregate: z = inv[d]*(acc + hws[d]) + b2
__global__ __launch_bounds__(512) void k_b2(const int* __restrict__ bbase,
                                            const int2* __restrict__ eb,
                                            const float* __restrict__ hws,
                                            const float* __restrict__ inv,
                                            const float* __restrict__ b2,
                                            float* __restrict__ z, int n) {
    __shared__ float acc[NPB * 17];
    __shared__ float b2s[16];
    int t = threadIdx.x, b = blockIdx.x;
    int nbase = b * NPB;
    for (int i = t; i < NPB * 17; i += 512) acc[i] = 0.0f;
    if (t < 16) b2s[t] = b2[t];
    __syncthreads();
    int beg = bbase[b], end = bbase[b + 1];
    int col = t & 15, g = t >> 4;  // 32 edge-groups of 16 lanes
    int i = beg + g;
    for (; i + 32 < end; i += 64) {
        int2 e0 = eb[i], e1 = eb[i + 32];
        float v0 = hws[(size_t)e0.x * 16 + col];
        float v1 = hws[(size_t)e1.x * 16 + col];
        atomicAdd(&acc[(e0.y - nbase) * 17 + col], v0);
        atomicAdd(&acc[(e1.y - nbase) * 17 + col], v1);
    }
    for (; i < end; i += 32) {
        int2 e = eb[i];
        float v = hws[(size_t)e.x * 16 + col];
        atomicAdd(&acc[(e.y - nbase) * 17 + col], v);
    }
    __syncthreads();
    for (int idx = t; idx < NPB * 16; idx += 512) {
        int nl = idx >> 4, c = idx & 15;
        int node = nbase + nl;
        if (node < n)
            z[(size_t)node * 16 + c] =
                inv[node] * (acc[nl * 17 + c] + hws[(size_t)node * 16 + c]) + b2s[c];
    }
}

__global__ void k_decode(const int* __restrict__ eli, const float* __restrict__ z,
                         float* __restrict__ out, int L) {
    int e = blockIdx.x * blockDim.x + threadIdx.x;
    if (e >= L) return;
    int a = eli[e], b = eli[L + e];
    const float4* za = (const float4*)(z + (size_t)a * 16);
    const float4* zb = (const float4*)(z + (size_t)b * 16);
    float s = 0.0f;
#pragma unroll
    for (int i = 0; i < 4; ++i) {
        float4 u = za[i], w = zb[i];
        s += u.x * w.x + u.y * w.y + u.z * w.z + u.w * w.w;
    }
    out[e] = s;
}

extern "C" void kernel_launch(void* const* d_in, const int* in_sizes, int n_in,
                              void* d_out, int out_size, void* d_ws, size_t ws_size,
                              hipStream_t stream) {
    const float* x   = (const float*)d_in[0];
    const int*   ei  = (const int*)d_in[1];
    const int*   eli = (const int*)d_in[2];
    const float* W1  = (const float*)d_in[3];
    const float* b1  = (const float*)d_in[4];
    const float* W2  = (const float*)d_in[5];
    const float* b2  = (const float*)d_in[6];
    float* out = (float*)d_out;

    int n = in_sizes[0] / 128;
    int E = in_sizes[1] / 2;
    int L = in_sizes[2] / 2;
    const int* src = ei;
    const int* dst = ei + E;
    int NB = (n + NPB - 1) / NPB;  // 782 for n=100k

    // ws layout: floats [inv n | xws 32n | hws 16n | z 16n] (65n, 8B-aligned
    // since n is even), then ints [eb 2E | bcnt NB | bbase NB+1 | bcursor NB]
    float* inv = (float*)d_ws;
    float* xws = inv + n;
    float* hws = xws + (size_t)n * 32;
    float* z   = hws + (size_t)n * 16;
    int2* eb     = (int2*)(z + (size_t)n * 16);
    int* bcnt    = (int*)(eb + E);
    int* bbase   = bcnt + NB;
    int* bcursor = bbase + NB + 1;

    k_zero<<<(NB + 255) / 256, 256, 0, stream>>>(bcnt, NB);
    k_a1<<<1024, 256, 0, stream>>>(dst, bcnt, E, NB);
    k_scanb<<<1, 256, 0, stream>>>(bcnt, bbase, bcursor, NB);
    k_a3<<<(E + A3_CHUNK - 1) / A3_CHUNK, 256, 0, stream>>>(src, dst, bcursor, eb, E, NB);
    k_deginv<<<NB, 256, 0, stream>>>(bbase, eb, inv, n);
    k_xw<<<(n + 7) / 8, 256, 0, stream>>>(x, W1, inv, xws, n);
    k_b1<<<NB, 512, 0, stream>>>(bbase, eb, xws, inv, b1, W2, hws, n);
    k_b2<<<NB, 512, 0, stream>>>(bbase, eb, hws, inv, b2, z, n);
    k_decode<<<(L + 255) / 256, 256, 0, stream>>>(eli, z, out, L);
}

// Round 4
// 389.783 us; speedup vs baseline: 3.2326x; 3.2326x over previous
//
#include <hip/hip_runtime.h>

// ---------------------------------------------------------------------------
// GCN link prediction, bucket-scatter -> per-bucket CSR -> per-node-wave gather.
//   Phase A: coarse bucket by dst>>7 (782 frontiers, L2-merged writes) with
//            packed u32 (src<<7 | dst&127)  [requires n <= 2^17]
//   Phase B: per-bucket block builds contiguous CSR (col, rp) + inv_sqrt(deg).
//   Agg: one wave per node, 4-deep pipelined gathers of prescaled rows.
// ---------------------------------------------------------------------------

#define NPB 128        // nodes per bucket
#define NBMAX 1024     // supports n <= 131072
#define A3_CHUNK 4096  // edges per scatter block (256 thr x 16)

__global__ void k_zero(int* __restrict__ p, int n) {
    int i = blockIdx.x * blockDim.x + threadIdx.x;
    if (i < n) p[i] = 0;
}

// Bucket histogram: LDS-privatized, ~NB global atomics per block.
__global__ __launch_bounds__(256) void k_a1(const int* __restrict__ dst,
                                            int* __restrict__ bcnt, int E, int NB) {
    __shared__ int lb[NBMAX];
    int t = threadIdx.x;
    for (int i = t; i < NB; i += 256) lb[i] = 0;
    __syncthreads();
    for (int e = blockIdx.x * 256 + t; e < E; e += gridDim.x * 256)
        atomicAdd(&lb[dst[e] >> 7], 1);
    __syncthreads();
    for (int i = t; i < NB; i += 256) {
        int c = lb[i];
        if (c) atomicAdd(&bcnt[i], c);
    }
}

// Single-block exclusive scan of bucket counts -> bbase, bcursor. NB <= 1024.
__global__ __launch_bounds__(256) void k_scanb(const int* __restrict__ bcnt,
                                               int* __restrict__ bbase,
                                               int* __restrict__ bcursor, int NB) {
    __shared__ int sh[256];
    int t = threadIdx.x;
    int i0 = t * 4;
    int v0 = (i0 + 0 < NB) ? bcnt[i0 + 0] : 0;
    int v1 = (i0 + 1 < NB) ? bcnt[i0 + 1] : 0;
    int v2 = (i0 + 2 < NB) ? bcnt[i0 + 2] : 0;
    int v3 = (i0 + 3 < NB) ? bcnt[i0 + 3] : 0;
    sh[t] = v0 + v1 + v2 + v3;
    __syncthreads();
    for (int off = 1; off < 256; off <<= 1) {
        int add = (t >= off) ? sh[t - off] : 0;
        __syncthreads();
        sh[t] += add;
        __syncthreads();
    }
    int run = (t > 0) ? sh[t - 1] : 0;
    if (i0 + 0 < NB) { bbase[i0 + 0] = run; bcursor[i0 + 0] = run; } run += v0;
    if (i0 + 1 < NB) { bbase[i0 + 1] = run; bcursor[i0 + 1] = run; } run += v1;
    if (i0 + 2 < NB) { bbase[i0 + 2] = run; bcursor[i0 + 2] = run; } run += v2;
    if (i0 + 3 < NB) { bbase[i0 + 3] = run; bcursor[i0 + 3] = run; }
    if (t == 255) bbase[NB] = sh[255];
}

// Bucketed scatter of packed (src<<7 | dst&127): per-block LDS hist -> one
// global cursor add per (block,bucket) -> LDS-ranked positions.
__global__ __launch_bounds__(256) void k_a3(const int* __restrict__ src,
                                            const int* __restrict__ dst,
                                            int* __restrict__ bcursor,
                                            unsigned* __restrict__ eb, int E, int NB) {
    __shared__ int lhist[NBMAX];
    __shared__ int lbase[NBMAX];
    int t = threadIdx.x;
    int e0 = blockIdx.x * A3_CHUNK;
    for (int i = t; i < NB; i += 256) lhist[i] = 0;
    __syncthreads();
    unsigned myp[16];
    int myb[16];
#pragma unroll
    for (int j = 0; j < 16; ++j) {
        int e = e0 + j * 256 + t;  // coalesced
        if (e < E) {
            int s = src[e], d = dst[e];
            myb[j] = d >> 7;
            myp[j] = ((unsigned)s << 7) | (unsigned)(d & 127);
            atomicAdd(&lhist[myb[j]], 1);
        } else {
            myb[j] = -1;
        }
    }
    __syncthreads();
    for (int i = t; i < NB; i += 256) {
        int c = lhist[i];
        lbase[i] = c ? atomicAdd(&bcursor[i], c) : 0;
        lhist[i] = 0;
    }
    __syncthreads();
#pragma unroll
    for (int j = 0; j < 16; ++j) {
        if (myb[j] >= 0) {
            int r = atomicAdd(&lhist[myb[j]], 1);
            eb[lbase[myb[j]] + r] = myp[j];
        }
    }
}

// Per-bucket CSR build: local hist -> scan -> contiguous col + rp + inv.
__global__ __launch_bounds__(256) void k_csr(const int* __restrict__ bbase,
                                             const unsigned* __restrict__ eb,
                                             int* __restrict__ col,
                                             int* __restrict__ rp,
                                             float* __restrict__ inv,
                                             int n, int E, int NB) {
    __shared__ int cnt[NPB];
    __shared__ int cur[NPB];
    int t = threadIdx.x, b = blockIdx.x;
    int nbase = b * NPB;
    int beg = bbase[b], end = bbase[b + 1];
    if (t < NPB) cnt[t] = 0;
    __syncthreads();
    for (int i = beg + t; i < end; i += 256) atomicAdd(&cnt[eb[i] & 127u], 1);
    __syncthreads();
    int c = (t < NPB) ? cnt[t] : 0;
    for (int off = 1; off < NPB; off <<= 1) {  // inclusive scan, threads 0..127
        int v = (t < NPB && t >= off) ? cnt[t - off] : 0;
        __syncthreads();
        if (t < NPB) cnt[t] += v;
        __syncthreads();
    }
    if (t < NPB) {
        int excl = cnt[t] - c;
        cur[t] = excl;
        int node = nbase + t;
        if (node < n) {
            rp[node] = beg + excl;
            inv[node] = rsqrtf((float)(c + 1));
        }
    }
    if (b == NB - 1 && t == 0) rp[n] = E;
    __syncthreads();
    for (int i = beg + t; i < end; i += 256) {
        unsigned p = eb[i];
        int r = atomicAdd(&cur[p & 127u], 1);
        col[beg + r] = (int)(p >> 7);
    }
}

// xws[n][32] = (x[n] @ W1) * inv[n]
__global__ __launch_bounds__(256) void k_xw(const float* __restrict__ x,
                                            const float* __restrict__ W1,
                                            const float* __restrict__ inv,
                                            float* __restrict__ xws, int n) {
    __shared__ float W1s[128 * 32];   // 16 KB
    __shared__ float xsh[8 * 128];    // 4 KB
    int t = threadIdx.x;
#pragma unroll
    for (int i = 0; i < 16; ++i) W1s[i * 256 + t] = W1[i * 256 + t];
    int base = blockIdx.x * 8;
    if (base + 8 <= n) {
        ((float4*)xsh)[t] = ((const float4*)(x + (size_t)base * 128))[t];
    } else {
        for (int i = t; i < 8 * 128; i += 256) {
            int node = base + (i >> 7);
            xsh[i] = (node < n) ? x[(size_t)node * 128 + (i & 127)] : 0.0f;
        }
    }
    __syncthreads();
    int j = t & 31, r = t >> 5;
    int node = base + r;
    if (node >= n) return;
    float sum = 0.0f;
#pragma unroll
    for (int k = 0; k < 128; ++k) sum += xsh[r * 128 + k] * W1s[k * 32 + j];
    xws[(size_t)node * 32 + j] = sum * inv[node];
}

// One wave per node, 4-deep pipelined gathers:
//   h[d] = relu(inv[d]*(xws[d] + sum_s xws[s]) + b1)
__global__ __launch_bounds__(256) void k_agg1(const int* __restrict__ rp,
                                              const int* __restrict__ cs,
                                              const float* __restrict__ xws,
                                              const float* __restrict__ inv,
                                              const float* __restrict__ b1,
                                              float* __restrict__ h, int n) {
    int w = (blockIdx.x * blockDim.x + threadIdx.x) >> 6;
    if (w >= n) return;
    int lane = threadIdx.x & 63;
    int col = lane & 31, g = lane >> 5;  // 2 groups of 32 lanes
    int beg = rp[w], end = rp[w + 1];
    float a0 = 0.0f, a1 = 0.0f, a2 = 0.0f, a3 = 0.0f;
    if (g == 0) a0 = xws[(size_t)w * 32 + col];  // self-loop
    int i = beg + g;
    for (; i + 6 < end; i += 8) {  // 4 independent gathers in flight per group
        int s0 = cs[i], s1 = cs[i + 2], s2 = cs[i + 4], s3 = cs[i + 6];
        a0 += xws[(size_t)s0 * 32 + col];
        a1 += xws[(size_t)s1 * 32 + col];
        a2 += xws[(size_t)s2 * 32 + col];
        a3 += xws[(size_t)s3 * 32 + col];
    }
    for (; i < end; i += 2) a0 += xws[(size_t)cs[i] * 32 + col];
    float acc = (a0 + a1) + (a2 + a3);
    acc += __shfl_xor(acc, 32);
    if (g == 0) h[(size_t)w * 32 + col] = fmaxf(inv[w] * acc + b1[col], 0.0f);
}

// hws[n][16] = (h @ W2) * inv[n]
__global__ __launch_bounds__(256) void k_hgemm(const float* __restrict__ h,
                                               const float* __restrict__ W2,
                                               const float* __restrict__ inv,
                                               float* __restrict__ hws, int n) {
    __shared__ float W2s[32 * 16];
    __shared__ float hsh[16 * 33];
    int t = threadIdx.x;
    W2s[t]       = W2[t];
    W2s[256 + t] = W2[256 + t];
    __syncthreads();
    int base = blockIdx.x * 16;
#pragma unroll
    for (int i = t; i < 512; i += 256) {
        int nl = i >> 5, kk = i & 31;
        int node = base + nl;
        hsh[nl * 33 + kk] = (node < n) ? h[(size_t)node * 32 + kk] : 0.0f;
    }
    __syncthreads();
    int k = t & 15, r = t >> 4;
    int node = base + r;
    if (node >= n) return;
    float sum = 0.0f;
#pragma unroll
    for (int kk = 0; kk < 32; ++kk) sum += hsh[r * 33 + kk] * W2s[kk * 16 + k];
    hws[(size_t)node * 16 + k] = sum * inv[node];
}

// One wave per node, 4 groups of 16 lanes, 4-deep pipelined gathers:
//   z[d] = inv[d]*(hws[d] + sum_s hws[s]) + b2
__global__ __launch_bounds__(256) void k_agg2(const int* __restrict__ rp,
                                              const int* __restrict__ cs,
                                              const float* __restrict__ hws,
                                              const float* __restrict__ inv,
                                              const float* __restrict__ b2,
                                              float* __restrict__ z, int n) {
    int w = (blockIdx.x * blockDim.x + threadIdx.x) >> 6;
    if (w >= n) return;
    int lane = threadIdx.x & 63;
    int col = lane & 15, g = lane >> 4;  // 4 groups of 16 lanes
    int beg = rp[w], end = rp[w + 1];
    float a0 = 0.0f, a1 = 0.0f, a2 = 0.0f, a3 = 0.0f;
    if (g == 0) a0 = hws[(size_t)w * 16 + col];  // self-loop
    int i = beg + g;
    for (; i + 12 < end; i += 16) {
        int s0 = cs[i], s1 = cs[i + 4], s2 = cs[i + 8], s3 = cs[i + 12];
        a0 += hws[(size_t)s0 * 16 + col];
        a1 += hws[(size_t)s1 * 16 + col];
        a2 += hws[(size_t)s2 * 16 + col];
        a3 += hws[(size_t)s3 * 16 + col];
    }
    for (; i < end; i += 4) a0 += hws[(size_t)cs[i] * 16 + col];
    float acc = (a0 + a1) + (a2 + a3);
    acc += __shfl_xor(acc, 32);
    acc += __shfl_xor(acc, 16);
    if (g == 0) z[(size_t)w * 16 + col] = inv[w] * acc + b2[col];
}

__global__ void k_decode(const int* __restrict__ eli, const float* __restrict__ z,
                         float* __restrict__ out, int L) {
    int e = blockIdx.x * blockDim.x + threadIdx.x;
    if (e >= L) return;
    int a = eli[e], b = eli[L + e];
    const float4* za = (const float4*)(z + (size_t)a * 16);
    const float4* zb = (const float4*)(z + (size_t)b * 16);
    float s = 0.0f;
#pragma unroll
    for (int i = 0; i < 4; ++i) {
        float4 u = za[i], w = zb[i];
        s += u.x * w.x + u.y * w.y + u.z * w.z + u.w * w.w;
    }
    out[e] = s;
}

extern "C" void kernel_launch(void* const* d_in, const int* in_sizes, int n_in,
                              void* d_out, int out_size, void* d_ws, size_t ws_size,
                              hipStream_t stream) {
    const float* x   = (const float*)d_in[0];
    const int*   ei  = (const int*)d_in[1];
    const int*   eli = (const int*)d_in[2];
    const float* W1  = (const float*)d_in[3];
    const float* b1  = (const float*)d_in[4];
    const float* W2  = (const float*)d_in[5];
    const float* b2  = (const float*)d_in[6];
    float* out = (float*)d_out;

    int n = in_sizes[0] / 128;
    int E = in_sizes[1] / 2;
    int L = in_sizes[2] / 2;
    const int* src = ei;
    const int* dst = ei + E;
    int NB = (n + NPB - 1) / NPB;  // 782 for n=100k (packing needs n <= 131072)

    // ws layout: floats [inv n | xws 32n | hws 16n | z 16n]
    // ints [eb E (reused as h: 32n floats, 32n <= E) | col E | rp n+1
    //       | bcnt NB | bbase NB+1 | bcursor NB]
    float* inv = (float*)d_ws;
    float* xws = inv + n;
    float* hws = xws + (size_t)n * 32;
    float* z   = hws + (size_t)n * 16;
    unsigned* eb = (unsigned*)(z + (size_t)n * 16);
    float* h     = (float*)eb;   // alias: eb dead after k_csr, h born in k_agg1
    int* col     = (int*)(eb + E);
    int* rp      = col + E;
    int* bcnt    = rp + n + 1;
    int* bbase   = bcnt + NB;
    int* bcursor = bbase + NB + 1;

    k_zero<<<(NB + 255) / 256, 256, 0, stream>>>(bcnt, NB);
    k_a1<<<1024, 256, 0, stream>>>(dst, bcnt, E, NB);
    k_scanb<<<1, 256, 0, stream>>>(bcnt, bbase, bcursor, NB);
    k_a3<<<(E + A3_CHUNK - 1) / A3_CHUNK, 256, 0, stream>>>(src, dst, bcursor, eb, E, NB);
    k_csr<<<NB, 256, 0, stream>>>(bbase, eb, col, rp, inv, n, E, NB);
    k_xw<<<(n + 7) / 8, 256, 0, stream>>>(x, W1, inv, xws, n);
    k_agg1<<<(n * 64 + 255) / 256, 256, 0, stream>>>(rp, col, xws, inv, b1, h, n);
    k_hgemm<<<(n + 15) / 16, 256, 0, stream>>>(h, W2, inv, hws, n);
    k_agg2<<<(n * 64 + 255) / 256, 256, 0, stream>>>(rp, col, hws, inv, b2, z, n);
    k_decode<<<(L + 255) / 256, 256, 0, stream>>>(eli, z, out, L);
}

// Round 5
// 348.118 us; speedup vs baseline: 3.6195x; 1.1197x over previous
//
#include <hip/hip_runtime.h>
#include <hip/hip_fp16.h>

// ---------------------------------------------------------------------------
// GCN link prediction, bucket-scatter -> per-bucket CSR -> per-node-wave gather.
//   fp16 gather tables: xws row 64 B (1 line/edge), hws table 3.2 MB (fits
//   per-XCD L2), z fp16 for decode. Layer-2 GEMM fused into agg1 epilogue
//   via wave butterfly + shfl broadcast.
// ---------------------------------------------------------------------------

#define NPB 128        // nodes per bucket
#define NBMAX 1024     // supports n <= 131072
#define A3_CHUNK 8192  // edges per scatter block (256 thr x 32)

__global__ void k_zero(int* __restrict__ p, int n) {
    int i = blockIdx.x * blockDim.x + threadIdx.x;
    if (i < n) p[i] = 0;
}

// Bucket histogram: LDS-privatized, ~NB global atomics per block.
__global__ __launch_bounds__(256) void k_a1(const int* __restrict__ dst,
                                            int* __restrict__ bcnt, int E, int NB) {
    __shared__ int lb[NBMAX];
    int t = threadIdx.x;
    for (int i = t; i < NB; i += 256) lb[i] = 0;
    __syncthreads();
    for (int e = blockIdx.x * 256 + t; e < E; e += gridDim.x * 256)
        atomicAdd(&lb[dst[e] >> 7], 1);
    __syncthreads();
    for (int i = t; i < NB; i += 256) {
        int c = lb[i];
        if (c) atomicAdd(&bcnt[i], c);
    }
}

// Single-block exclusive scan of bucket counts -> bbase, bcursor. NB <= 1024.
__global__ __launch_bounds__(256) void k_scanb(const int* __restrict__ bcnt,
                                               int* __restrict__ bbase,
                                               int* __restrict__ bcursor, int NB) {
    __shared__ int sh[256];
    int t = threadIdx.x;
    int i0 = t * 4;
    int v0 = (i0 + 0 < NB) ? bcnt[i0 + 0] : 0;
    int v1 = (i0 + 1 < NB) ? bcnt[i0 + 1] : 0;
    int v2 = (i0 + 2 < NB) ? bcnt[i0 + 2] : 0;
    int v3 = (i0 + 3 < NB) ? bcnt[i0 + 3] : 0;
    sh[t] = v0 + v1 + v2 + v3;
    __syncthreads();
    for (int off = 1; off < 256; off <<= 1) {
        int add = (t >= off) ? sh[t - off] : 0;
        __syncthreads();
        sh[t] += add;
        __syncthreads();
    }
    int run = (t > 0) ? sh[t - 1] : 0;
    if (i0 + 0 < NB) { bbase[i0 + 0] = run; bcursor[i0 + 0] = run; } run += v0;
    if (i0 + 1 < NB) { bbase[i0 + 1] = run; bcursor[i0 + 1] = run; } run += v1;
    if (i0 + 2 < NB) { bbase[i0 + 2] = run; bcursor[i0 + 2] = run; } run += v2;
    if (i0 + 3 < NB) { bbase[i0 + 3] = run; bcursor[i0 + 3] = run; }
    if (t == 255) bbase[NB] = sh[255];
}

// Bucketed scatter of packed (src<<7 | dst&127): per-block LDS hist -> one
// global cursor add per (block,bucket) -> LDS-ranked positions.
__global__ __launch_bounds__(256) void k_a3(const int* __restrict__ src,
                                            const int* __restrict__ dst,
                                            int* __restrict__ bcursor,
                                            unsigned* __restrict__ eb, int E, int NB) {
    __shared__ int lhist[NBMAX];
    __shared__ int lbase[NBMAX];
    int t = threadIdx.x;
    int e0 = blockIdx.x * A3_CHUNK;
    for (int i = t; i < NB; i += 256) lhist[i] = 0;
    __syncthreads();
    unsigned myp[32];
    int myb[32];
#pragma unroll
    for (int j = 0; j < 32; ++j) {
        int e = e0 + j * 256 + t;  // coalesced
        if (e < E) {
            int s = src[e], d = dst[e];
            myb[j] = d >> 7;
            myp[j] = ((unsigned)s << 7) | (unsigned)(d & 127);
            atomicAdd(&lhist[myb[j]], 1);
        } else {
            myb[j] = -1;
        }
    }
    __syncthreads();
    for (int i = t; i < NB; i += 256) {
        int c = lhist[i];
        lbase[i] = c ? atomicAdd(&bcursor[i], c) : 0;
        lhist[i] = 0;
    }
    __syncthreads();
#pragma unroll
    for (int j = 0; j < 32; ++j) {
        if (myb[j] >= 0) {
            int r = atomicAdd(&lhist[myb[j]], 1);
            eb[lbase[myb[j]] + r] = myp[j];
        }
    }
}

// Per-bucket CSR build: local hist -> scan -> contiguous col + rp + inv.
__global__ __launch_bounds__(256) void k_csr(const int* __restrict__ bbase,
                                             const unsigned* __restrict__ eb,
                                             int* __restrict__ col,
                                             int* __restrict__ rp,
                                             float* __restrict__ inv,
                                             int n, int E, int NB) {
    __shared__ int cnt[NPB];
    __shared__ int cur[NPB];
    int t = threadIdx.x, b = blockIdx.x;
    int nbase = b * NPB;
    int beg = bbase[b], end = bbase[b + 1];
    if (t < NPB) cnt[t] = 0;
    __syncthreads();
    for (int i = beg + t; i < end; i += 256) atomicAdd(&cnt[eb[i] & 127u], 1);
    __syncthreads();
    int c = (t < NPB) ? cnt[t] : 0;
    for (int off = 1; off < NPB; off <<= 1) {  // inclusive scan over 128
        int v = (t < NPB && t >= off) ? cnt[t - off] : 0;
        __syncthreads();
        if (t < NPB) cnt[t] += v;
        __syncthreads();
    }
    if (t < NPB) {
        int excl = cnt[t] - c;
        cur[t] = excl;
        int node = nbase + t;
        if (node < n) {
            rp[node] = beg + excl;
            inv[node] = rsqrtf((float)(c + 1));
        }
    }
    if (b == NB - 1 && t == 0) rp[n] = E;
    __syncthreads();
    for (int i = beg + t; i < end; i += 256) {
        unsigned p = eb[i];
        int r = atomicAdd(&cur[p & 127u], 1);
        col[beg + r] = (int)(p >> 7);
    }
}

// xws[n][32] (fp16) = (x[n] @ W1) * inv[n]; W1 transposed in LDS (stride 130).
__global__ __launch_bounds__(256) void k_xw(const float* __restrict__ x,
                                            const float* __restrict__ W1,
                                            const float* __restrict__ inv,
                                            __half* __restrict__ xws, int n) {
    __shared__ float W1t[32 * 130];  // 16.6 KB, 2-way-max bank aliasing (free)
    __shared__ float xsh[8 * 128];   // 4 KB
    int t = threadIdx.x;
#pragma unroll
    for (int i = 0; i < 16; ++i) {
        int idx = i * 256 + t;  // idx = k*32 + j
        W1t[(idx & 31) * 130 + (idx >> 5)] = W1[idx];
    }
    int base = blockIdx.x * 8;
    if (base + 8 <= n) {
        ((float4*)xsh)[t] = ((const float4*)(x + (size_t)base * 128))[t];
    } else {
        for (int i = t; i < 8 * 128; i += 256) {
            int node = base + (i >> 7);
            xsh[i] = (node < n) ? x[(size_t)node * 128 + (i & 127)] : 0.0f;
        }
    }
    __syncthreads();
    int j = t & 31, r = t >> 5;
    int node = base + r;
    if (node >= n) return;
    const float* xr = &xsh[r * 128];
    const float* wr = &W1t[j * 130];
    float sum = 0.0f;
#pragma unroll
    for (int k = 0; k < 128; k += 4) {
        float4 xv = *(const float4*)&xr[k];
        float2 w0 = *(const float2*)&wr[k];
        float2 w1 = *(const float2*)&wr[k + 2];
        sum += xv.x * w0.x + xv.y * w0.y + xv.z * w1.x + xv.w * w1.y;
    }
    xws[(size_t)node * 32 + j] = __float2half(sum * inv[node]);
}

// One wave per node, 4 groups x 16 lanes (half2 each), 16 edges in flight.
// h = relu(inv*(sum)+b1) via butterfly; fused hws = (h@W2)*inv epilogue.
__global__ __launch_bounds__(256) void k_agg1(const int* __restrict__ rp,
                                              const int* __restrict__ cs,
                                              const __half2* __restrict__ X,  // xws [n*16]
                                              const float* __restrict__ inv,
                                              const float* __restrict__ b1,
                                              const float* __restrict__ W2,
                                              __half* __restrict__ hws, int n) {
    int w = (blockIdx.x * blockDim.x + threadIdx.x) >> 6;
    if (w >= n) return;
    int lane = threadIdx.x & 63;
    int c = lane & 15, g = lane >> 4;
    int beg = rp[w], end = rp[w + 1];
    float a0x = 0, a0y = 0, a1x = 0, a1y = 0, a2x = 0, a2y = 0, a3x = 0, a3y = 0;
    if (g == 0) {
        float2 v = __half22float2(X[(size_t)w * 16 + c]);  // self-loop
        a0x = v.x; a0y = v.y;
    }
    int i = beg + g;
    for (; i + 12 < end; i += 16) {
        int s0 = cs[i], s1 = cs[i + 4], s2 = cs[i + 8], s3 = cs[i + 12];
        float2 v0 = __half22float2(X[(size_t)s0 * 16 + c]);
        float2 v1 = __half22float2(X[(size_t)s1 * 16 + c]);
        float2 v2 = __half22float2(X[(size_t)s2 * 16 + c]);
        float2 v3 = __half22float2(X[(size_t)s3 * 16 + c]);
        a0x += v0.x; a0y += v0.y; a1x += v1.x; a1y += v1.y;
        a2x += v2.x; a2y += v2.y; a3x += v3.x; a3y += v3.y;
    }
    for (; i < end; i += 4) {
        float2 v = __half22float2(X[(size_t)cs[i] * 16 + c]);
        a0x += v.x; a0y += v.y;
    }
    float ax = (a0x + a1x) + (a2x + a3x);
    float ay = (a0y + a1y) + (a2y + a3y);
    ax += __shfl_xor(ax, 16); ay += __shfl_xor(ay, 16);
    ax += __shfl_xor(ax, 32); ay += __shfl_xor(ay, 32);
    float invw = inv[w];
    float2 bv = ((const float2*)b1)[c];
    float hx = fmaxf(invw * ax + bv.x, 0.0f);  // h[2c]
    float hy = fmaxf(invw * ay + bv.y, 0.0f);  // h[2c+1]
    // fused: hws[w][c] = inv[w] * sum_k h[k] * W2[k][c]
    float s = 0.0f;
#pragma unroll
    for (int k = 0; k < 16; ++k) {
        float hkx = __shfl(hx, k);
        float hky = __shfl(hy, k);
        s += hkx * W2[(2 * k) * 16 + c] + hky * W2[(2 * k + 1) * 16 + c];
    }
    if (lane < 16) hws[(size_t)w * 16 + c] = __float2half(s * invw);
}

// One wave per node, 8 groups x 8 lanes (half2 each), 32 edges in flight.
// z = inv*(sum)+b2 stored fp16.
__global__ __launch_bounds__(256) void k_agg2(const int* __restrict__ rp,
                                              const int* __restrict__ cs,
                                              const __half2* __restrict__ H,  // hws [n*8]
                                              const float* __restrict__ inv,
                                              const float* __restrict__ b2,
                                              __half2* __restrict__ z, int n) {
    int w = (blockIdx.x * blockDim.x + threadIdx.x) >> 6;
    if (w >= n) return;
    int lane = threadIdx.x & 63;
    int c = lane & 7, g = lane >> 3;
    int beg = rp[w], end = rp[w + 1];
    float a0x = 0, a0y = 0, a1x = 0, a1y = 0, a2x = 0, a2y = 0, a3x = 0, a3y = 0;
    if (g == 0) {
        float2 v = __half22float2(H[(size_t)w * 8 + c]);  // self-loop
        a0x = v.x; a0y = v.y;
    }
    int i = beg + g;
    for (; i + 24 < end; i += 32) {
        int s0 = cs[i], s1 = cs[i + 8], s2 = cs[i + 16], s3 = cs[i + 24];
        float2 v0 = __half22float2(H[(size_t)s0 * 8 + c]);
        float2 v1 = __half22float2(H[(size_t)s1 * 8 + c]);
        float2 v2 = __half22float2(H[(size_t)s2 * 8 + c]);
        float2 v3 = __half22float2(H[(size_t)s3 * 8 + c]);
        a0x += v0.x; a0y += v0.y; a1x += v1.x; a1y += v1.y;
        a2x += v2.x; a2y += v2.y; a3x += v3.x; a3y += v3.y;
    }
    for (; i < end; i += 8) {
        float2 v = __half22float2(H[(size_t)cs[i] * 8 + c]);
        a0x += v.x; a0y += v.y;
    }
    float ax = (a0x + a1x) + (a2x + a3x);
    float ay = (a0y + a1y) + (a2y + a3y);
    ax += __shfl_xor(ax, 8);  ay += __shfl_xor(ay, 8);
    ax += __shfl_xor(ax, 16); ay += __shfl_xor(ay, 16);
    ax += __shfl_xor(ax, 32); ay += __shfl_xor(ay, 32);
    float invw = inv[w];
    float2 bv = ((const float2*)b2)[c];
    if (lane < 8)
        z[(size_t)w * 8 + c] = __floats2half2_rn(invw * ax + bv.x, invw * ay + bv.y);
}

__device__ inline float dot8h(uint4 u, uint4 v) {
    const __half2* pu = (const __half2*)&u;
    const __half2* pv = (const __half2*)&v;
    float s = 0.0f;
#pragma unroll
    for (int i = 0; i < 4; ++i) {
        float2 a = __half22float2(pu[i]);
        float2 b = __half22float2(pv[i]);
        s += a.x * b.x + a.y * b.y;
    }
    return s;
}

__global__ void k_decode(const int* __restrict__ eli, const uint4* __restrict__ z4,
                         float* __restrict__ out, int L) {
    int e = blockIdx.x * blockDim.x + threadIdx.x;
    if (e >= L) return;
    int a = eli[e], b = eli[L + e];
    uint4 ua0 = z4[(size_t)a * 2], ua1 = z4[(size_t)a * 2 + 1];
    uint4 ub0 = z4[(size_t)b * 2], ub1 = z4[(size_t)b * 2 + 1];
    out[e] = dot8h(ua0, ub0) + dot8h(ua1, ub1);
}

extern "C" void kernel_launch(void* const* d_in, const int* in_sizes, int n_in,
                              void* d_out, int out_size, void* d_ws, size_t ws_size,
                              hipStream_t stream) {
    const float* x   = (const float*)d_in[0];
    const int*   ei  = (const int*)d_in[1];
    const int*   eli = (const int*)d_in[2];
    const float* W1  = (const float*)d_in[3];
    const float* b1  = (const float*)d_in[4];
    const float* W2  = (const float*)d_in[5];
    const float* b2  = (const float*)d_in[6];
    float* out = (float*)d_out;

    int n = in_sizes[0] / 128;
    int E = in_sizes[1] / 2;
    int L = in_sizes[2] / 2;
    const int* src = ei;
    const int* dst = ei + E;
    int NB = (n + NPB - 1) / NPB;  // 782 for n=100k (packing needs n <= 131072)

    // ws layout: halfs [xws 32n | hws 16n | z 16n] (z offset 96n B, 16B-aligned)
    // then floats [inv n], ints [rp n+1 | eb E | col E | bcnt NB | bbase NB+1 | bcursor NB]
    __half* xws = (__half*)d_ws;
    __half* hws = xws + (size_t)n * 32;
    __half* z   = hws + (size_t)n * 16;
    float* inv  = (float*)(z + (size_t)n * 16);
    int* rp      = (int*)(inv + n);
    unsigned* eb = (unsigned*)(rp + n + 1);
    int* col     = (int*)(eb + E);
    int* bcnt    = col + E;
    int* bbase   = bcnt + NB;
    int* bcursor = bbase + NB + 1;

    k_zero<<<(NB + 255) / 256, 256, 0, stream>>>(bcnt, NB);
    k_a1<<<512, 256, 0, stream>>>(dst, bcnt, E, NB);
    k_scanb<<<1, 256, 0, stream>>>(bcnt, bbase, bcursor, NB);
    k_a3<<<(E + A3_CHUNK - 1) / A3_CHUNK, 256, 0, stream>>>(src, dst, bcursor, eb, E, NB);
    k_csr<<<NB, 256, 0, stream>>>(bbase, eb, col, rp, inv, n, E, NB);
    k_xw<<<(n + 7) / 8, 256, 0, stream>>>(x, W1, inv, xws, n);
    k_agg1<<<(n * 64 + 255) / 256, 256, 0, stream>>>(rp, col, (const __half2*)xws, inv, b1, W2, hws, n);
    k_agg2<<<(n * 64 + 255) / 256, 256, 0, stream>>>(rp, col, (const __half2*)hws, inv, b2, (__half2*)z, n);
    k_decode<<<(L + 255) / 256, 256, 0, stream>>>(eli, (const uint4*)z, out, L);
}

// Round 6
// 340.396 us; speedup vs baseline: 3.7016x; 1.0227x over previous
//
#include <hip/hip_runtime.h>
#include <hip/hip_fp16.h>

// ---------------------------------------------------------------------------
// GCN link prediction. bucket-scatter -> per-bucket CSR -> per-node-wave gather.
// R6: layer-1 aggregation column-split into two passes so each gather table is
// 3.2 MB (L2-resident per XCD, like the fast agg2); 4-lane/8B gather groups
// (16 groups x 2-deep = 32 chains/wave); register-tiled xw; replicated-counter
// CSR ranking.
// ---------------------------------------------------------------------------

#define NPB 128        // nodes per bucket
#define NBMAX 1024     // supports n <= 131072
#define A3_CHUNK 8192  // edges per scatter block (256 thr x 32)

// Bucket histogram: LDS-privatized, ~NB global atomics per block.
__global__ __launch_bounds__(256) void k_a1(const int* __restrict__ dst,
                                            int* __restrict__ bcnt, int E, int NB) {
    __shared__ int lb[NBMAX];
    int t = threadIdx.x;
    for (int i = t; i < NB; i += 256) lb[i] = 0;
    __syncthreads();
    for (int e = blockIdx.x * 256 + t; e < E; e += gridDim.x * 256)
        atomicAdd(&lb[dst[e] >> 7], 1);
    __syncthreads();
    for (int i = t; i < NB; i += 256) {
        int c = lb[i];
        if (c) atomicAdd(&bcnt[i], c);
    }
}

// Single-block exclusive scan of bucket counts -> bbase, bcursor. NB <= 1024.
__global__ __launch_bounds__(256) void k_scanb(const int* __restrict__ bcnt,
                                               int* __restrict__ bbase,
                                               int* __restrict__ bcursor, int NB) {
    __shared__ int sh[256];
    int t = threadIdx.x;
    int i0 = t * 4;
    int v0 = (i0 + 0 < NB) ? bcnt[i0 + 0] : 0;
    int v1 = (i0 + 1 < NB) ? bcnt[i0 + 1] : 0;
    int v2 = (i0 + 2 < NB) ? bcnt[i0 + 2] : 0;
    int v3 = (i0 + 3 < NB) ? bcnt[i0 + 3] : 0;
    sh[t] = v0 + v1 + v2 + v3;
    __syncthreads();
    for (int off = 1; off < 256; off <<= 1) {
        int add = (t >= off) ? sh[t - off] : 0;
        __syncthreads();
        sh[t] += add;
        __syncthreads();
    }
    int run = (t > 0) ? sh[t - 1] : 0;
    if (i0 + 0 < NB) { bbase[i0 + 0] = run; bcursor[i0 + 0] = run; } run += v0;
    if (i0 + 1 < NB) { bbase[i0 + 1] = run; bcursor[i0 + 1] = run; } run += v1;
    if (i0 + 2 < NB) { bbase[i0 + 2] = run; bcursor[i0 + 2] = run; } run += v2;
    if (i0 + 3 < NB) { bbase[i0 + 3] = run; bcursor[i0 + 3] = run; }
    if (t == 255) bbase[NB] = sh[255];
}

// Bucketed scatter of packed (src<<7 | dst&127): per-block LDS hist -> one
// global cursor add per (block,bucket) -> LDS-ranked positions.
__global__ __launch_bounds__(256) void k_a3(const int* __restrict__ src,
                                            const int* __restrict__ dst,
                                            int* __restrict__ bcursor,
                                            unsigned* __restrict__ eb, int E, int NB) {
    __shared__ int lhist[NBMAX];
    __shared__ int lbase[NBMAX];
    int t = threadIdx.x;
    int e0 = blockIdx.x * A3_CHUNK;
    for (int i = t; i < NB; i += 256) lhist[i] = 0;
    __syncthreads();
    unsigned myp[32];
    int myb[32];
#pragma unroll
    for (int j = 0; j < 32; ++j) {
        int e = e0 + j * 256 + t;  // coalesced
        if (e < E) {
            int s = src[e], d = dst[e];
            myb[j] = d >> 7;
            myp[j] = ((unsigned)s << 7) | (unsigned)(d & 127);
            atomicAdd(&lhist[myb[j]], 1);
        } else {
            myb[j] = -1;
        }
    }
    __syncthreads();
    for (int i = t; i < NB; i += 256) {
        int c = lhist[i];
        lbase[i] = c ? atomicAdd(&bcursor[i], c) : 0;
        lhist[i] = 0;
    }
    __syncthreads();
#pragma unroll
    for (int j = 0; j < 32; ++j) {
        if (myb[j] >= 0) {
            int r = atomicAdd(&lhist[myb[j]], 1);
            eb[lbase[myb[j]] + r] = myp[j];
        }
    }
}

// Per-bucket CSR build, per-wave replicated counters (4x128) to cut LDS-atomic
// contention 4x on both hist and rank passes. Same edge->replica map both passes.
__global__ __launch_bounds__(256) void k_csr(const int* __restrict__ bbase,
                                             const unsigned* __restrict__ eb,
                                             int* __restrict__ col,
                                             int* __restrict__ rp,
                                             float* __restrict__ inv,
                                             int n, int E, int NB) {
    __shared__ int cnt[4][NPB];
    __shared__ int cur[4][NPB];
    __shared__ int tot[NPB];
    int t = threadIdx.x, b = blockIdx.x;
    int wv = t >> 6;  // wave id = replica
    int nbase = b * NPB;
    int beg = bbase[b], end = bbase[b + 1];
    for (int i = t; i < 4 * NPB; i += 256) ((int*)cnt)[i] = 0;
    __syncthreads();
    for (int i = beg + t; i < end; i += 256) atomicAdd(&cnt[wv][eb[i] & 127u], 1);
    __syncthreads();
    int c = 0;
    if (t < NPB) {
        c = cnt[0][t] + cnt[1][t] + cnt[2][t] + cnt[3][t];
        tot[t] = c;
    }
    __syncthreads();
    for (int off = 1; off < NPB; off <<= 1) {  // inclusive scan over 128
        int v = (t < NPB && t >= off) ? tot[t - off] : 0;
        __syncthreads();
        if (t < NPB) tot[t] += v;
        __syncthreads();
    }
    if (t < NPB) {
        int excl = tot[t] - c;
        int run = beg + excl;
#pragma unroll
        for (int r = 0; r < 4; ++r) { cur[r][t] = run; run += cnt[r][t]; }
        int node = nbase + t;
        if (node < n) {
            rp[node] = beg + excl;
            inv[node] = rsqrtf((float)(c + 1));
        }
    }
    if (b == NB - 1 && t == 0) rp[n] = E;
    __syncthreads();
    for (int i = beg + t; i < end; i += 256) {
        unsigned p = eb[i];
        int pos = atomicAdd(&cur[wv][p & 127u], 1);
        col[pos] = (int)(p >> 7);
    }
}

// xw: 128 nodes/block, 4x4 register tile (256 thr), x staged transposed in LDS.
// Outputs split: Xa = cols 0..15, Xb = cols 16..31 (fp16, 4-half chunks).
__global__ __launch_bounds__(256) void k_xw(const float* __restrict__ x,
                                            const float* __restrict__ W1,
                                            const float* __restrict__ inv,
                                            uint2* __restrict__ Xa,
                                            uint2* __restrict__ Xb, int n) {
    __shared__ float xsh[128 * 128];  // [k][node], 64 KB
    __shared__ float W1s[128 * 32];   // [k][col], 16 KB
    int t = threadIdx.x;
    int base = blockIdx.x * 128;
#pragma unroll
    for (int i = 0; i < 16; ++i) W1s[i * 256 + t] = W1[i * 256 + t];
    {
        int nl = t >> 1, kh = (t & 1) * 64;
        int node = base + nl;
        if (node < n) {
            const float4* xr = (const float4*)(x + (size_t)node * 128 + kh);
#pragma unroll
            for (int kk = 0; kk < 16; ++kk) {
                float4 v = xr[kk];
                int k = kh + kk * 4;
                xsh[(k + 0) * 128 + nl] = v.x;
                xsh[(k + 1) * 128 + nl] = v.y;
                xsh[(k + 2) * 128 + nl] = v.z;
                xsh[(k + 3) * 128 + nl] = v.w;
            }
        } else {
#pragma unroll
            for (int kk = 0; kk < 64; ++kk) xsh[(kh + kk) * 128 + nl] = 0.0f;
        }
    }
    __syncthreads();
    int tc = t & 7, tr = t >> 3;  // nodes 4*tr.., cols 4*tc..
    float acc[4][4] = {};
#pragma unroll 8
    for (int k = 0; k < 128; ++k) {
        float4 xv = *(const float4*)&xsh[k * 128 + 4 * tr];
        float4 wv = *(const float4*)&W1s[k * 32 + 4 * tc];
        acc[0][0] += xv.x * wv.x; acc[0][1] += xv.x * wv.y; acc[0][2] += xv.x * wv.z; acc[0][3] += xv.x * wv.w;
        acc[1][0] += xv.y * wv.x; acc[1][1] += xv.y * wv.y; acc[1][2] += xv.y * wv.z; acc[1][3] += xv.y * wv.w;
        acc[2][0] += xv.z * wv.x; acc[2][1] += xv.z * wv.y; acc[2][2] += xv.z * wv.z; acc[2][3] += xv.z * wv.w;
        acc[3][0] += xv.w * wv.x; acc[3][1] += xv.w * wv.y; acc[3][2] += xv.w * wv.z; acc[3][3] += xv.w * wv.w;
    }
    uint2* T = (tc < 4) ? Xa : Xb;
    int q = tc & 3;
#pragma unroll
    for (int i = 0; i < 4; ++i) {
        int node = base + 4 * tr + i;
        if (node < n) {
            float iw = inv[node];
            __half2 p0 = __floats2half2_rn(acc[i][0] * iw, acc[i][1] * iw);
            __half2 p1 = __floats2half2_rn(acc[i][2] * iw, acc[i][3] * iw);
            uint2 u;
            u.x = *(unsigned*)&p0;
            u.y = *(unsigned*)&p1;
            T[(size_t)node * 4 + q] = u;
        }
    }
}

// --- gather-sum over a 16-half-per-row table: 16 groups x 4 lanes x 8 B ------
__device__ __forceinline__ float4 gload(const uint2* __restrict__ T, int srow, int q) {
    uint2 u = T[(size_t)srow * 4 + q];
    float2 f0 = __half22float2(*(__half2*)&u.x);
    float2 f1 = __half22float2(*(__half2*)&u.y);
    return make_float4(f0.x, f0.y, f1.x, f1.y);
}

__device__ __forceinline__ float4 gather16(const int* __restrict__ rp,
                                           const int* __restrict__ col,
                                           const uint2* __restrict__ T,
                                           int w, int lane) {
    int q = lane & 3, g = lane >> 2;
    int beg = rp[w], end = rp[w + 1];
    float4 a0 = make_float4(0.f, 0.f, 0.f, 0.f), a1 = a0;
    if (g == 0) a0 = gload(T, w, q);  // self-loop
    int i = beg + g;
    for (; i + 16 < end; i += 32) {  // 2-deep x 16 groups = 32 chains in flight
        int s0 = col[i], s1 = col[i + 16];
        float4 v0 = gload(T, s0, q);
        float4 v1 = gload(T, s1, q);
        a0.x += v0.x; a0.y += v0.y; a0.z += v0.z; a0.w += v0.w;
        a1.x += v1.x; a1.y += v1.y; a1.z += v1.z; a1.w += v1.w;
    }
    for (; i < end; i += 16) {
        float4 v = gload(T, col[i], q);
        a0.x += v.x; a0.y += v.y; a0.z += v.z; a0.w += v.w;
    }
    float4 acc = make_float4(a0.x + a1.x, a0.y + a1.y, a0.z + a1.z, a0.w + a1.w);
#pragma unroll
    for (int m = 4; m < 64; m <<= 1) {
        acc.x += __shfl_xor(acc.x, m);
        acc.y += __shfl_xor(acc.y, m);
        acc.z += __shfl_xor(acc.z, m);
        acc.w += __shfl_xor(acc.w, m);
    }
    return acc;  // all lanes: column-chunk totals for cols 4q..4q+3
}

// Pass A: hA[w][0:16] = relu(inv*(agg cols 0..15) + b1[0:16])  (fp16)
__global__ __launch_bounds__(256) void k_aggA(const int* __restrict__ rp,
                                              const int* __restrict__ col,
                                              const uint2* __restrict__ Xa,
                                              const float* __restrict__ inv,
                                              const float* __restrict__ b1,
                                              uint2* __restrict__ hA, int n) {
    int w = (blockIdx.x * 256 + threadIdx.x) >> 6;
    if (w >= n) return;
    int lane = threadIdx.x & 63, q = lane & 3;
    float4 acc = gather16(rp, col, Xa, w, lane);
    float iw = inv[w];
    float4 bb = *(const float4*)(b1 + 4 * q);
    if (lane < 4) {
        __half2 p0 = __floats2half2_rn(fmaxf(iw * acc.x + bb.x, 0.f),
                                       fmaxf(iw * acc.y + bb.y, 0.f));
        __half2 p1 = __floats2half2_rn(fmaxf(iw * acc.z + bb.z, 0.f),
                                       fmaxf(iw * acc.w + bb.w, 0.f));
        uint2 u;
        u.x = *(unsigned*)&p0;
        u.y = *(unsigned*)&p1;
        hA[(size_t)w * 4 + q] = u;
    }
}

// Pass B: agg cols 16..31, reload hA, fused hws = (h @ W2) * inv  (fp16 out).
__global__ __launch_bounds__(256) void k_aggB(const int* __restrict__ rp,
                                              const int* __restrict__ col,
                                              const uint2* __restrict__ Xb,
                                              const uint2* __restrict__ hA,
                                              const float* __restrict__ inv,
                                              const float* __restrict__ b1,
                                              const float* __restrict__ W2,
                                              __half* __restrict__ hws, int n) {
    int w = (blockIdx.x * 256 + threadIdx.x) >> 6;
    if (w >= n) return;
    int lane = threadIdx.x & 63, q = lane & 3;
    float4 acc = gather16(rp, col, Xb, w, lane);
    float iw = inv[w];
    float4 bb = *(const float4*)(b1 + 16 + 4 * q);
    float hh[4];
    hh[0] = fmaxf(iw * acc.x + bb.x, 0.f);
    hh[1] = fmaxf(iw * acc.y + bb.y, 0.f);
    hh[2] = fmaxf(iw * acc.z + bb.z, 0.f);
    hh[3] = fmaxf(iw * acc.w + bb.w, 0.f);
    uint2 u = hA[(size_t)w * 4 + q];
    float2 f0 = __half22float2(*(__half2*)&u.x);
    float2 f1 = __half22float2(*(__half2*)&u.y);
    float hl[4] = {f0.x, f0.y, f1.x, f1.y};
    // hws[w][c] = iw * sum_k h[k]*W2[k][c]; h[4qq+j]=hl from lane qq, h[16+4qq+j]=hh
    int c = lane & 15;
    float s = 0.f;
#pragma unroll
    for (int qq = 0; qq < 4; ++qq) {
#pragma unroll
        for (int j = 0; j < 4; ++j) {
            float hlo = __shfl(hl[j], qq);
            float hhi = __shfl(hh[j], qq);
            s += hlo * W2[(4 * qq + j) * 16 + c] + hhi * W2[(16 + 4 * qq + j) * 16 + c];
        }
    }
    if (lane < 16) hws[(size_t)w * 16 + c] = __float2half(s * iw);
}

// Layer 2: z = inv*(agg hws) + b2  (fp16, 16 halves/node)
__global__ __launch_bounds__(256) void k_agg2(const int* __restrict__ rp,
                                              const int* __restrict__ col,
                                              const uint2* __restrict__ H,
                                              const float* __restrict__ inv,
                                              const float* __restrict__ b2,
                                              uint2* __restrict__ z, int n) {
    int w = (blockIdx.x * 256 + threadIdx.x) >> 6;
    if (w >= n) return;
    int lane = threadIdx.x & 63, q = lane & 3;
    float4 acc = gather16(rp, col, H, w, lane);
    float iw = inv[w];
    float4 bb = *(const float4*)(b2 + 4 * q);
    if (lane < 4) {
        __half2 p0 = __floats2half2_rn(iw * acc.x + bb.x, iw * acc.y + bb.y);
        __half2 p1 = __floats2half2_rn(iw * acc.z + bb.z, iw * acc.w + bb.w);
        uint2 u;
        u.x = *(unsigned*)&p0;
        u.y = *(unsigned*)&p1;
        z[(size_t)w * 4 + q] = u;
    }
}

__device__ __forceinline__ float dot8h(uint4 u, uint4 v) {
    const __half2* pu = (const __half2*)&u;
    const __half2* pv = (const __half2*)&v;
    float s = 0.0f;
#pragma unroll
    for (int i = 0; i < 4; ++i) {
        float2 a = __half22float2(pu[i]);
        float2 b = __half22float2(pv[i]);
        s += a.x * b.x + a.y * b.y;
    }
    return s;
}

__global__ void k_decode(const int* __restrict__ eli, const uint4* __restrict__ z4,
                         float* __restrict__ out, int L) {
    int e = blockIdx.x * blockDim.x + threadIdx.x;
    if (e >= L) return;
    int a = eli[e], b = eli[L + e];
    uint4 ua0 = z4[(size_t)a * 2], ua1 = z4[(size_t)a * 2 + 1];
    uint4 ub0 = z4[(size_t)b * 2], ub1 = z4[(size_t)b * 2 + 1];
    out[e] = dot8h(ua0, ub0) + dot8h(ua1, ub1);
}

extern "C" void kernel_launch(void* const* d_in, const int* in_sizes, int n_in,
                              void* d_out, int out_size, void* d_ws, size_t ws_size,
                              hipStream_t stream) {
    const float* x   = (const float*)d_in[0];
    const int*   ei  = (const int*)d_in[1];
    const int*   eli = (const int*)d_in[2];
    const float* W1  = (const float*)d_in[3];
    const float* b1  = (const float*)d_in[4];
    const float* W2  = (const float*)d_in[5];
    const float* b2  = (const float*)d_in[6];
    float* out = (float*)d_out;

    int n = in_sizes[0] / 128;
    int E = in_sizes[1] / 2;
    int L = in_sizes[2] / 2;
    const int* src = ei;
    const int* dst = ei + E;
    int NB = (n + NPB - 1) / NPB;  // 782 for n=100k (packing needs n <= 131072)

    // ws: uint2 tables [Xa 4n | Xb 4n | hA 4n | hws(4n) | z 4n] (each 32n B),
    // then floats [inv n], ints [rp n+1 | eb E | col E | bcnt NB | bbase NB+1 | bcursor NB]
    uint2* Xa = (uint2*)d_ws;
    uint2* Xb = Xa + (size_t)n * 4;
    uint2* hA = Xb + (size_t)n * 4;
    uint2* hws = hA + (size_t)n * 4;
    uint2* z   = hws + (size_t)n * 4;
    float* inv = (float*)(z + (size_t)n * 4);
    int* rp      = (int*)(inv + n);
    unsigned* eb = (unsigned*)(rp + n + 1);
    int* col     = (int*)(eb + E);
    int* bcnt    = col + E;
    int* bbase   = bcnt + NB;
    int* bcursor = bbase + NB + 1;

    hipMemsetAsync(bcnt, 0, NB * sizeof(int), stream);
    k_a1<<<512, 256, 0, stream>>>(dst, bcnt, E, NB);
    k_scanb<<<1, 256, 0, stream>>>(bcnt, bbase, bcursor, NB);
    k_a3<<<(E + A3_CHUNK - 1) / A3_CHUNK, 256, 0, stream>>>(src, dst, bcursor, eb, E, NB);
    k_csr<<<NB, 256, 0, stream>>>(bbase, eb, col, rp, inv, n, E, NB);
    k_xw<<<(n + 127) / 128, 256, 0, stream>>>(x, W1, inv, Xa, Xb, n);
    k_aggA<<<(n + 3) / 4, 256, 0, stream>>>(rp, col, Xa, inv, b1, hA, n);
    k_aggB<<<(n + 3) / 4, 256, 0, stream>>>(rp, col, Xb, hA, inv, b1, W2, (__half*)hws, n);
    k_agg2<<<(n + 3) / 4, 256, 0, stream>>>(rp, col, hws, inv, b2, z, n);
    k_decode<<<(L + 255) / 256, 256, 0, stream>>>(eli, (const uint4*)z, out, L);
}

// Round 7
// 315.392 us; speedup vs baseline: 3.9951x; 1.0793x over previous
//
#include <hip/hip_runtime.h>
#include <hip/hip_fp16.h>

// ---------------------------------------------------------------------------
// GCN link prediction. bucket-scatter -> per-bucket CSR -> per-node-wave gather.
// R7: single-pass layer-1 gather (64 B fp16 rows, uint4 per lane, 16 edges in
// flight per wave-instr x 2-deep); v_fma_mix accumulation (1 VALU/half);
// persistent grid-stride waves with W2 held in registers (cheap fused GEMM
// epilogue); fdot2 decode.
// ---------------------------------------------------------------------------

#define NPB 128        // nodes per bucket
#define NBMAX 1024     // supports n <= 131072
#define A3_CHUNK 8192  // edges per scatter block (256 thr x 32)

// Bucket histogram: LDS-privatized, ~NB global atomics per block.
__global__ __launch_bounds__(256) void k_a1(const int* __restrict__ dst,
                                            int* __restrict__ bcnt, int E, int NB) {
    __shared__ int lb[NBMAX];
    int t = threadIdx.x;
    for (int i = t; i < NB; i += 256) lb[i] = 0;
    __syncthreads();
    for (int e = blockIdx.x * 256 + t; e < E; e += gridDim.x * 256)
        atomicAdd(&lb[dst[e] >> 7], 1);
    __syncthreads();
    for (int i = t; i < NB; i += 256) {
        int c = lb[i];
        if (c) atomicAdd(&bcnt[i], c);
    }
}

// Single-block exclusive scan of bucket counts -> bbase, bcursor. NB <= 1024.
__global__ __launch_bounds__(256) void k_scanb(const int* __restrict__ bcnt,
                                               int* __restrict__ bbase,
                                               int* __restrict__ bcursor, int NB) {
    __shared__ int sh[256];
    int t = threadIdx.x;
    int i0 = t * 4;
    int v0 = (i0 + 0 < NB) ? bcnt[i0 + 0] : 0;
    int v1 = (i0 + 1 < NB) ? bcnt[i0 + 1] : 0;
    int v2 = (i0 + 2 < NB) ? bcnt[i0 + 2] : 0;
    int v3 = (i0 + 3 < NB) ? bcnt[i0 + 3] : 0;
    sh[t] = v0 + v1 + v2 + v3;
    __syncthreads();
    for (int off = 1; off < 256; off <<= 1) {
        int add = (t >= off) ? sh[t - off] : 0;
        __syncthreads();
        sh[t] += add;
        __syncthreads();
    }
    int run = (t > 0) ? sh[t - 1] : 0;
    if (i0 + 0 < NB) { bbase[i0 + 0] = run; bcursor[i0 + 0] = run; } run += v0;
    if (i0 + 1 < NB) { bbase[i0 + 1] = run; bcursor[i0 + 1] = run; } run += v1;
    if (i0 + 2 < NB) { bbase[i0 + 2] = run; bcursor[i0 + 2] = run; } run += v2;
    if (i0 + 3 < NB) { bbase[i0 + 3] = run; bcursor[i0 + 3] = run; }
    if (t == 255) bbase[NB] = sh[255];
}

// Bucketed scatter of packed (src<<7 | dst&127): per-block LDS hist -> one
// global cursor add per (block,bucket) -> LDS-ranked positions.
__global__ __launch_bounds__(256) void k_a3(const int* __restrict__ src,
                                            const int* __restrict__ dst,
                                            int* __restrict__ bcursor,
                                            unsigned* __restrict__ eb, int E, int NB) {
    __shared__ int lhist[NBMAX];
    __shared__ int lbase[NBMAX];
    int t = threadIdx.x;
    int e0 = blockIdx.x * A3_CHUNK;
    for (int i = t; i < NB; i += 256) lhist[i] = 0;
    __syncthreads();
    unsigned myp[32];
    int myb[32];
#pragma unroll
    for (int j = 0; j < 32; ++j) {
        int e = e0 + j * 256 + t;  // coalesced
        if (e < E) {
            int s = src[e], d = dst[e];
            myb[j] = d >> 7;
            myp[j] = ((unsigned)s << 7) | (unsigned)(d & 127);
            atomicAdd(&lhist[myb[j]], 1);
        } else {
            myb[j] = -1;
        }
    }
    __syncthreads();
    for (int i = t; i < NB; i += 256) {
        int c = lhist[i];
        lbase[i] = c ? atomicAdd(&bcursor[i], c) : 0;
        lhist[i] = 0;
    }
    __syncthreads();
#pragma unroll
    for (int j = 0; j < 32; ++j) {
        if (myb[j] >= 0) {
            int r = atomicAdd(&lhist[myb[j]], 1);
            eb[lbase[myb[j]] + r] = myp[j];
        }
    }
}

// Per-bucket CSR build, per-wave replicated counters (4x128).
__global__ __launch_bounds__(256) void k_csr(const int* __restrict__ bbase,
                                             const unsigned* __restrict__ eb,
                                             int* __restrict__ col,
                                             int* __restrict__ rp,
                                             float* __restrict__ inv,
                                             int n, int E, int NB) {
    __shared__ int cnt[4][NPB];
    __shared__ int cur[4][NPB];
    __shared__ int tot[NPB];
    int t = threadIdx.x, b = blockIdx.x;
    int wv = t >> 6;  // wave id = replica
    int nbase = b * NPB;
    int beg = bbase[b], end = bbase[b + 1];
    for (int i = t; i < 4 * NPB; i += 256) ((int*)cnt)[i] = 0;
    __syncthreads();
    for (int i = beg + t; i < end; i += 256) atomicAdd(&cnt[wv][eb[i] & 127u], 1);
    __syncthreads();
    int c = 0;
    if (t < NPB) {
        c = cnt[0][t] + cnt[1][t] + cnt[2][t] + cnt[3][t];
        tot[t] = c;
    }
    __syncthreads();
    for (int off = 1; off < NPB; off <<= 1) {
        int v = (t < NPB && t >= off) ? tot[t - off] : 0;
        __syncthreads();
        if (t < NPB) tot[t] += v;
        __syncthreads();
    }
    if (t < NPB) {
        int excl = tot[t] - c;
        int run = beg + excl;
#pragma unroll
        for (int r = 0; r < 4; ++r) { cur[r][t] = run; run += cnt[r][t]; }
        int node = nbase + t;
        if (node < n) {
            rp[node] = beg + excl;
            inv[node] = rsqrtf((float)(c + 1));
        }
    }
    if (b == NB - 1 && t == 0) rp[n] = E;
    __syncthreads();
    for (int i = beg + t; i < end; i += 256) {
        unsigned p = eb[i];
        int pos = atomicAdd(&cur[wv][p & 127u], 1);
        col[pos] = (int)(p >> 7);
    }
}

// xw: 128 nodes/block, 4x4 register tile, x staged transposed in LDS.
// Output: X[n][32] fp16, written as uint2 (4-half) chunks, tc = chunk 0..7.
__global__ __launch_bounds__(256) void k_xw(const float* __restrict__ x,
                                            const float* __restrict__ W1,
                                            const float* __restrict__ inv,
                                            uint2* __restrict__ X, int n) {
    __shared__ float xsh[128 * 128];  // [k][node], 64 KB
    __shared__ float W1s[128 * 32];   // [k][col], 16 KB
    int t = threadIdx.x;
    int base = blockIdx.x * 128;
#pragma unroll
    for (int i = 0; i < 16; ++i) W1s[i * 256 + t] = W1[i * 256 + t];
    {
        int nl = t >> 1, kh = (t & 1) * 64;
        int node = base + nl;
        if (node < n) {
            const float4* xr = (const float4*)(x + (size_t)node * 128 + kh);
#pragma unroll
            for (int kk = 0; kk < 16; ++kk) {
                float4 v = xr[kk];
                int k = kh + kk * 4;
                xsh[(k + 0) * 128 + nl] = v.x;
                xsh[(k + 1) * 128 + nl] = v.y;
                xsh[(k + 2) * 128 + nl] = v.z;
                xsh[(k + 3) * 128 + nl] = v.w;
            }
        } else {
#pragma unroll
            for (int kk = 0; kk < 64; ++kk) xsh[(kh + kk) * 128 + nl] = 0.0f;
        }
    }
    __syncthreads();
    int tc = t & 7, tr = t >> 3;  // nodes 4*tr.., cols 4*tc..
    float acc[4][4] = {};
#pragma unroll 8
    for (int k = 0; k < 128; ++k) {
        float4 xv = *(const float4*)&xsh[k * 128 + 4 * tr];
        float4 wv = *(const float4*)&W1s[k * 32 + 4 * tc];
        acc[0][0] += xv.x * wv.x; acc[0][1] += xv.x * wv.y; acc[0][2] += xv.x * wv.z; acc[0][3] += xv.x * wv.w;
        acc[1][0] += xv.y * wv.x; acc[1][1] += xv.y * wv.y; acc[1][2] += xv.y * wv.z; acc[1][3] += xv.y * wv.w;
        acc[2][0] += xv.z * wv.x; acc[2][1] += xv.z * wv.y; acc[2][2] += xv.z * wv.z; acc[2][3] += xv.z * wv.w;
        acc[3][0] += xv.w * wv.x; acc[3][1] += xv.w * wv.y; acc[3][2] += xv.w * wv.z; acc[3][3] += xv.w * wv.w;
    }
#pragma unroll
    for (int i = 0; i < 4; ++i) {
        int node = base + 4 * tr + i;
        if (node < n) {
            float iw = inv[node];
            __half2 p0 = __floats2half2_rn(acc[i][0] * iw, acc[i][1] * iw);
            __half2 p1 = __floats2half2_rn(acc[i][2] * iw, acc[i][3] * iw);
            uint2 u;
            u.x = *(unsigned*)&p0;
            u.y = *(unsigned*)&p1;
            X[(size_t)node * 8 + tc] = u;
        }
    }
}

// acc[j] += f32(h[j]) — written so LLVM can form v_fma_mix_f32 (x*1.0+acc).
__device__ __forceinline__ void add8(float* a, uint4 v) {
    union { uint4 u; __half h[8]; } cv;
    cv.u = v;
#pragma unroll
    for (int j = 0; j < 8; ++j) a[j] = fmaf(__half2float(cv.h[j]), 1.0f, a[j]);
}

__device__ __forceinline__ void add4(float* a, uint2 v) {
    union { uint2 u; __half h[4]; } cv;
    cv.u = v;
#pragma unroll
    for (int j = 0; j < 4; ++j) a[j] = fmaf(__half2float(cv.h[j]), 1.0f, a[j]);
}

// Layer 1, single pass, persistent waves. Gather 64 B rows (uint4 x 4 lanes),
// h = relu(inv*sum + b1), fused hws = (h @ W2)*inv with W2 in registers.
__global__ __launch_bounds__(256) void k_agg1(const int* __restrict__ rp,
                                              const int* __restrict__ col,
                                              const uint4* __restrict__ X4,
                                              const float* __restrict__ inv,
                                              const float* __restrict__ b1,
                                              const float* __restrict__ W2,
                                              __half* __restrict__ hws, int n) {
    int wid = (blockIdx.x * 256 + threadIdx.x) >> 6;
    int nw = (gridDim.x * 256) >> 6;
    int lane = threadIdx.x & 63;
    int q = lane & 3, g = lane >> 2;       // gather: 16 groups x 4 lanes
    int c = lane & 15, r = lane >> 4;      // epilogue: 4 replicas x 16 cols
    float w2r[8], bb[8];
#pragma unroll
    for (int j = 0; j < 8; ++j) w2r[j] = W2[(8 * r + j) * 16 + c];  // once/wave
#pragma unroll
    for (int j = 0; j < 8; ++j) bb[j] = b1[8 * q + j];
    for (int w = wid; w < n; w += nw) {
        int beg = rp[w], end = rp[w + 1];
        float a0[8] = {}, a1[8] = {};
        if (g == 0) add8(a0, X4[(size_t)w * 4 + q]);  // self-loop
        int i = beg + g;
        for (; i + 16 < end; i += 32) {  // 2-deep x 16 groups = 32 in flight
            int s0 = col[i], s1 = col[i + 16];
            uint4 v0 = X4[(size_t)s0 * 4 + q];
            uint4 v1 = X4[(size_t)s1 * 4 + q];
            add8(a0, v0);
            add8(a1, v1);
        }
        for (; i < end; i += 16) add8(a0, X4[(size_t)col[i] * 4 + q]);
#pragma unroll
        for (int j = 0; j < 8; ++j) a0[j] += a1[j];
#pragma unroll
        for (int m = 4; m < 64; m <<= 1)
#pragma unroll
            for (int j = 0; j < 8; ++j) a0[j] += __shfl_xor(a0[j], m);
        float iw = inv[w];
        float h[8];
#pragma unroll
        for (int j = 0; j < 8; ++j) h[j] = fmaxf(iw * a0[j] + bb[j], 0.0f);
        // hws[w][c] = iw * sum_k h[k] * W2[k][c]; lane (r,c) does k=8r..8r+7
        float s = 0.0f;
#pragma unroll
        for (int j = 0; j < 8; ++j) s += __shfl(h[j], r) * w2r[j];
        s += __shfl_xor(s, 16);
        s += __shfl_xor(s, 32);
        if (lane < 16) hws[(size_t)w * 16 + c] = __float2half(s * iw);
    }
}

// Layer 2, persistent waves: z = inv*(agg hws) + b2 (fp16 out, 32 B rows).
__global__ __launch_bounds__(256) void k_agg2(const int* __restrict__ rp,
                                              const int* __restrict__ col,
                                              const uint2* __restrict__ H2,
                                              const float* __restrict__ inv,
                                              const float* __restrict__ b2,
                                              uint2* __restrict__ z, int n) {
    int wid = (blockIdx.x * 256 + threadIdx.x) >> 6;
    int nw = (gridDim.x * 256) >> 6;
    int lane = threadIdx.x & 63;
    int q = lane & 3, g = lane >> 2;  // 16 groups x 4 lanes x 8 B
    float bb[4];
#pragma unroll
    for (int j = 0; j < 4; ++j) bb[j] = b2[4 * q + j];
    for (int w = wid; w < n; w += nw) {
        int beg = rp[w], end = rp[w + 1];
        float a0[4] = {}, a1[4] = {};
        if (g == 0) add4(a0, H2[(size_t)w * 4 + q]);  // self-loop
        int i = beg + g;
        for (; i + 16 < end; i += 32) {
            int s0 = col[i], s1 = col[i + 16];
            uint2 v0 = H2[(size_t)s0 * 4 + q];
            uint2 v1 = H2[(size_t)s1 * 4 + q];
            add4(a0, v0);
            add4(a1, v1);
        }
        for (; i < end; i += 16) add4(a0, H2[(size_t)col[i] * 4 + q]);
#pragma unroll
        for (int j = 0; j < 4; ++j) a0[j] += a1[j];
#pragma unroll
        for (int m = 4; m < 64; m <<= 1)
#pragma unroll
            for (int j = 0; j < 4; ++j) a0[j] += __shfl_xor(a0[j], m);
        float iw = inv[w];
        if (lane < 4) {
            __half2 p0 = __floats2half2_rn(iw * a0[0] + bb[0], iw * a0[1] + bb[1]);
            __half2 p1 = __floats2half2_rn(iw * a0[2] + bb[2], iw * a0[3] + bb[3]);
            uint2 u;
            u.x = *(unsigned*)&p0;
            u.y = *(unsigned*)&p1;
            z[(size_t)w * 4 + q] = u;
        }
    }
}

__device__ __forceinline__ float dot8h(uint4 u, uint4 v, float s) {
    const __half2* pu = (const __half2*)&u;
    const __half2* pv = (const __half2*)&v;
#pragma unroll
    for (int i = 0; i < 4; ++i) {
#if __has_builtin(__builtin_amdgcn_fdot2)
        s = __builtin_amdgcn_fdot2(pu[i], pv[i], s, false);
#else
        float2 a = __half22float2(pu[i]);
        float2 b = __half22float2(pv[i]);
        s += a.x * b.x + a.y * b.y;
#endif
    }
    return s;
}

__global__ void k_decode(const int* __restrict__ eli, const uint4* __restrict__ z4,
                         float* __restrict__ out, int L) {
    int e = blockIdx.x * blockDim.x + threadIdx.x;
    if (e >= L) return;
    int a = eli[e], b = eli[L + e];
    uint4 ua0 = z4[(size_t)a * 2], ua1 = z4[(size_t)a * 2 + 1];
    uint4 ub0 = z4[(size_t)b * 2], ub1 = z4[(size_t)b * 2 + 1];
    out[e] = dot8h(ua1, ub1, dot8h(ua0, ub0, 0.0f));
}

extern "C" void kernel_launch(void* const* d_in, const int* in_sizes, int n_in,
                              void* d_out, int out_size, void* d_ws, size_t ws_size,
                              hipStream_t stream) {
    const float* x   = (const float*)d_in[0];
    const int*   ei  = (const int*)d_in[1];
    const int*   eli = (const int*)d_in[2];
    const float* W1  = (const float*)d_in[3];
    const float* b1  = (const float*)d_in[4];
    const float* W2  = (const float*)d_in[5];
    const float* b2  = (const float*)d_in[6];
    float* out = (float*)d_out;

    int n = in_sizes[0] / 128;
    int E = in_sizes[1] / 2;
    int L = in_sizes[2] / 2;
    const int* src = ei;
    const int* dst = ei + E;
    int NB = (n + NPB - 1) / NPB;  // 782 for n=100k (packing needs n <= 131072)

    // ws: X [n][32]h (64n B) | hws [n][16]h (32n B) | z [n][16]h (32n B)
    //     | inv n f | rp n+1 | eb E | col E | bcnt NB | bbase NB+1 | bcursor NB
    uint2* X   = (uint2*)d_ws;                       // 8 uint2 per node
    uint2* hws = X + (size_t)n * 8;                  // 4 uint2 per node
    uint2* z   = hws + (size_t)n * 4;
    float* inv = (float*)(z + (size_t)n * 4);
    int* rp      = (int*)(inv + n);
    unsigned* eb = (unsigned*)(rp + n + 1);
    int* col     = (int*)(eb + E);
    int* bcnt    = col + E;
    int* bbase   = bcnt + NB;
    int* bcursor = bbase + NB + 1;

    hipMemsetAsync(bcnt, 0, NB * sizeof(int), stream);
    k_a1<<<512, 256, 0, stream>>>(dst, bcnt, E, NB);
    k_scanb<<<1, 256, 0, stream>>>(bcnt, bbase, bcursor, NB);
    k_a3<<<(E + A3_CHUNK - 1) / A3_CHUNK, 256, 0, stream>>>(src, dst, bcursor, eb, E, NB);
    k_csr<<<NB, 256, 0, stream>>>(bbase, eb, col, rp, inv, n, E, NB);
    k_xw<<<(n + 127) / 128, 256, 0, stream>>>(x, W1, inv, X, n);
    k_agg1<<<2048, 256, 0, stream>>>(rp, col, (const uint4*)X, inv, b1, W2, (__half*)hws, n);
    k_agg2<<<2048, 256, 0, stream>>>(rp, col, hws, inv, b2, z, n);
    k_decode<<<(L + 255) / 256, 256, 0, stream>>>(eli, (const uint4*)z, out, L);
}

// Round 8
// 279.618 us; speedup vs baseline: 4.5062x; 1.1279x over previous
//
#include <hip/hip_runtime.h>
#include <hip/hip_fp16.h>

// ---------------------------------------------------------------------------
// GCN link prediction. bucket-scatter -> per-bucket padded CSR -> per-node
// 8-lane-group gather with ZERO cross-lane reduction (lane owns its columns).
// Node lists padded to x4 (dummy src = node n, a zero row) so the gather loop
// is branch-free with aligned int4 col loads and 4-deep row-load ILP.
// ---------------------------------------------------------------------------

#define NPB 128        // nodes per bucket
#define NBMAX 1024     // supports n <= 131072
#define A3_CHUNK 8192  // edges per scatter block (256 thr x 32)

// Bucket histogram: LDS-privatized, ~NB global atomics per block.
__global__ __launch_bounds__(256) void k_a1(const int* __restrict__ dst,
                                            int* __restrict__ bcnt, int E, int NB) {
    __shared__ int lb[NBMAX];
    int t = threadIdx.x;
    for (int i = t; i < NB; i += 256) lb[i] = 0;
    __syncthreads();
    for (int e = blockIdx.x * 256 + t; e < E; e += gridDim.x * 256)
        atomicAdd(&lb[dst[e] >> 7], 1);
    __syncthreads();
    for (int i = t; i < NB; i += 256) {
        int c = lb[i];
        if (c) atomicAdd(&bcnt[i], c);
    }
}

// Scans: raw (bbase/bcursor for eb) and padded+slack, 4-aligned (pbase for col).
__global__ __launch_bounds__(256) void k_scanb(const int* __restrict__ bcnt,
                                               int* __restrict__ bbase,
                                               int* __restrict__ bcursor,
                                               int* __restrict__ pbase, int NB) {
    __shared__ int sh[256];
    int t = threadIdx.x;
    int i0 = t * 4;
    int v[4], p[4];
#pragma unroll
    for (int j = 0; j < 4; ++j) {
        v[j] = (i0 + j < NB) ? bcnt[i0 + j] : 0;
        p[j] = ((v[j] + 3) & ~3) + 384;  // slack for per-node x4 padding
    }
    sh[t] = v[0] + v[1] + v[2] + v[3];
    __syncthreads();
    for (int off = 1; off < 256; off <<= 1) {
        int add = (t >= off) ? sh[t - off] : 0;
        __syncthreads();
        sh[t] += add;
        __syncthreads();
    }
    int run = (t > 0) ? sh[t - 1] : 0;
    int total = sh[255];
#pragma unroll
    for (int j = 0; j < 4; ++j) {
        if (i0 + j < NB) { bbase[i0 + j] = run; bcursor[i0 + j] = run; }
        run += v[j];
    }
    if (t == 255) bbase[NB] = total;
    __syncthreads();
    sh[t] = p[0] + p[1] + p[2] + p[3];
    __syncthreads();
    for (int off = 1; off < 256; off <<= 1) {
        int add = (t >= off) ? sh[t - off] : 0;
        __syncthreads();
        sh[t] += add;
        __syncthreads();
    }
    int run2 = (t > 0) ? sh[t - 1] : 0;
#pragma unroll
    for (int j = 0; j < 4; ++j) {
        if (i0 + j < NB) pbase[i0 + j] = run2;
        run2 += p[j];
    }
}

// Bucketed scatter of packed (src<<7 | dst&127): per-block LDS hist -> one
// global cursor add per (block,bucket) -> LDS-ranked positions.
__global__ __launch_bounds__(256) void k_a3(const int* __restrict__ src,
                                            const int* __restrict__ dst,
                                            int* __restrict__ bcursor,
                                            unsigned* __restrict__ eb, int E, int NB) {
    __shared__ int lhist[NBMAX];
    __shared__ int lbase[NBMAX];
    int t = threadIdx.x;
    int e0 = blockIdx.x * A3_CHUNK;
    for (int i = t; i < NB; i += 256) lhist[i] = 0;
    __syncthreads();
    unsigned myp[32];
    int myb[32];
#pragma unroll
    for (int j = 0; j < 32; ++j) {
        int e = e0 + j * 256 + t;  // coalesced
        if (e < E) {
            int s = src[e], d = dst[e];
            myb[j] = d >> 7;
            myp[j] = ((unsigned)s << 7) | (unsigned)(d & 127);
            atomicAdd(&lhist[myb[j]], 1);
        } else {
            myb[j] = -1;
        }
    }
    __syncthreads();
    for (int i = t; i < NB; i += 256) {
        int c = lhist[i];
        lbase[i] = c ? atomicAdd(&bcursor[i], c) : 0;
        lhist[i] = 0;
    }
    __syncthreads();
#pragma unroll
    for (int j = 0; j < 32; ++j) {
        if (myb[j] >= 0) {
            int r = atomicAdd(&lhist[myb[j]], 1);
            eb[lbase[myb[j]] + r] = myp[j];
        }
    }
}

// Per-bucket padded CSR: hist (4-replica) -> scan of padded counts -> contiguous
// col with x4-padded per-node segments (gaps = dummy node n) + rpbeg/rpcnt/inv.
__global__ __launch_bounds__(256) void k_csr(const int* __restrict__ bbase,
                                             const int* __restrict__ pbase,
                                             const unsigned* __restrict__ eb,
                                             int* __restrict__ col,
                                             int* __restrict__ rpbeg,
                                             int* __restrict__ rpcnt,
                                             float* __restrict__ inv,
                                             int n, int NB) {
    __shared__ int cnt[4][NPB];
    __shared__ int cur[4][NPB];
    __shared__ int tot[NPB];
    int t = threadIdx.x, b = blockIdx.x;
    int wv = t >> 6;  // wave id = replica
    int nbase = b * NPB;
    int beg = bbase[b], end = bbase[b + 1];
    int pb = pbase[b];
    for (int i = t; i < 4 * NPB; i += 256) ((int*)cnt)[i] = 0;
    __syncthreads();
    for (int i = beg + t; i < end; i += 256) atomicAdd(&cnt[wv][eb[i] & 127u], 1);
    __syncthreads();
    int c = 0, pc = 0;
    if (t < NPB) {
        c = cnt[0][t] + cnt[1][t] + cnt[2][t] + cnt[3][t];
        pc = (c + 3) & ~3;
        tot[t] = pc;
    }
    __syncthreads();
    for (int off = 1; off < NPB; off <<= 1) {  // inclusive scan over 128
        int v = (t < NPB && t >= off) ? tot[t - off] : 0;
        __syncthreads();
        if (t < NPB) tot[t] += v;
        __syncthreads();
    }
    if (t < NPB) {
        int base_t = pb + (tot[t] - pc);
        int run = base_t;
#pragma unroll
        for (int r = 0; r < 4; ++r) { cur[r][t] = run; run += cnt[r][t]; }
        int node = nbase + t;
        if (node < n) {
            rpbeg[node] = base_t;
            rpcnt[node] = pc;
            inv[node] = rsqrtf((float)(c + 1));
            for (int j = c; j < pc; ++j) col[base_t + j] = n;  // dummy zero row
        }
    }
    __syncthreads();
    for (int i = beg + t; i < end; i += 256) {
        unsigned p = eb[i];
        int pos = atomicAdd(&cur[wv][p & 127u], 1);
        col[pos] = (int)(p >> 7);
    }
}

// xw: 128 nodes/block, 4x4 register tile, x staged transposed in LDS.
// X[n+1][32] fp16 (uint2 = 4-half chunks); block 0 zeroes dummy rows X[n], hws[n].
__global__ __launch_bounds__(256) void k_xw(const float* __restrict__ x,
                                            const float* __restrict__ W1,
                                            const float* __restrict__ inv,
                                            uint2* __restrict__ X,
                                            unsigned* __restrict__ hws0, int n) {
    __shared__ float xsh[128 * 128];  // [k][node], 64 KB
    __shared__ float W1s[128 * 32];   // [k][col], 16 KB
    int t = threadIdx.x;
    int base = blockIdx.x * 128;
#pragma unroll
    for (int i = 0; i < 16; ++i) W1s[i * 256 + t] = W1[i * 256 + t];
    {
        int nl = t >> 1, kh = (t & 1) * 64;
        int node = base + nl;
        if (node < n) {
            const float4* xr = (const float4*)(x + (size_t)node * 128 + kh);
#pragma unroll
            for (int kk = 0; kk < 16; ++kk) {
                float4 v = xr[kk];
                int k = kh + kk * 4;
                xsh[(k + 0) * 128 + nl] = v.x;
                xsh[(k + 1) * 128 + nl] = v.y;
                xsh[(k + 2) * 128 + nl] = v.z;
                xsh[(k + 3) * 128 + nl] = v.w;
            }
        } else {
#pragma unroll
            for (int kk = 0; kk < 64; ++kk) xsh[(kh + kk) * 128 + nl] = 0.0f;
        }
    }
    if (blockIdx.x == 0) {  // dummy rows for padded-CSR gap entries
        if (t < 8) X[(size_t)n * 8 + t] = make_uint2(0u, 0u);
        else if (t < 16) hws0[(size_t)n * 8 + (t - 8)] = 0u;
    }
    __syncthreads();
    int tc = t & 7, tr = t >> 3;  // nodes 4*tr.., cols 4*tc..
    float acc[4][4] = {};
#pragma unroll 8
    for (int k = 0; k < 128; ++k) {
        float4 xv = *(const float4*)&xsh[k * 128 + 4 * tr];
        float4 wv = *(const float4*)&W1s[k * 32 + 4 * tc];
        acc[0][0] += xv.x * wv.x; acc[0][1] += xv.x * wv.y; acc[0][2] += xv.x * wv.z; acc[0][3] += xv.x * wv.w;
        acc[1][0] += xv.y * wv.x; acc[1][1] += xv.y * wv.y; acc[1][2] += xv.y * wv.z; acc[1][3] += xv.y * wv.w;
        acc[2][0] += xv.z * wv.x; acc[2][1] += xv.z * wv.y; acc[2][2] += xv.z * wv.z; acc[2][3] += xv.z * wv.w;
        acc[3][0] += xv.w * wv.x; acc[3][1] += xv.w * wv.y; acc[3][2] += xv.w * wv.z; acc[3][3] += xv.w * wv.w;
    }
#pragma unroll
    for (int i = 0; i < 4; ++i) {
        int node = base + 4 * tr + i;
        if (node < n) {
            float iw = inv[node];
            __half2 p0 = __floats2half2_rn(acc[i][0] * iw, acc[i][1] * iw);
            __half2 p1 = __floats2half2_rn(acc[i][2] * iw, acc[i][3] * iw);
            uint2 u;
            u.x = *(unsigned*)&p0;
            u.y = *(unsigned*)&p1;
            X[(size_t)node * 8 + tc] = u;
        }
    }
}

// acc[j] += f32(h[j]) — shaped for v_fma_mix_f32 (x*1.0+acc, exact).
__device__ __forceinline__ void add4h(float* a, uint2 v) {
    union { uint2 u; __half h[4]; } cv;
    cv.u = v;
#pragma unroll
    for (int j = 0; j < 4; ++j) a[j] = fmaf(__half2float(cv.h[j]), 1.0f, a[j]);
}

__device__ __forceinline__ void add2h(float* a, unsigned v) {
    union { unsigned u; __half h[2]; } cv;
    cv.u = v;
    a[0] = fmaf(__half2float(cv.h[0]), 1.0f, a[0]);
    a[1] = fmaf(__half2float(cv.h[1]), 1.0f, a[1]);
}

// Layer 1: one node per 8-lane group; lane owns 4 cols (uint2 of the 64 B row).
// Private f32 accumulation (no cross-lane reduce). Branch-free x4 edge loop,
// 4-deep row-load ILP. Epilogue: relu+bias in-lane, W2 GEMM via group shfl.
__global__ __launch_bounds__(256) void k_agg1(const int* __restrict__ rpbeg,
                                              const int* __restrict__ rpcnt,
                                              const int* __restrict__ col,
                                              const uint2* __restrict__ X2,
                                              const float* __restrict__ inv,
                                              const float* __restrict__ b1,
                                              const float* __restrict__ W2,
                                              __half2* __restrict__ hws, int n) {
    __shared__ float W2s[512];
    int t = threadIdx.x;
    W2s[t] = W2[t];
    W2s[256 + t] = W2[256 + t];
    __syncthreads();
    int w = (blockIdx.x * 256 + t) >> 3;
    if (w >= n) return;  // group-uniform (8 lanes share w)
    int q = t & 7;
    int grpbase = (t & 63) & 56;
    float bb[4];
#pragma unroll
    for (int j = 0; j < 4; ++j) bb[j] = b1[4 * q + j];
    int beg = rpbeg[w], endp = beg + rpcnt[w];
    float a[4] = {};
    add4h(a, X2[(size_t)w * 8 + q]);  // self-loop
    for (int i = beg; i < endp; i += 4) {
        int4 c4 = *(const int4*)(col + i);  // 16B-aligned by construction
        uint2 v0 = X2[(size_t)c4.x * 8 + q];
        uint2 v1 = X2[(size_t)c4.y * 8 + q];
        uint2 v2 = X2[(size_t)c4.z * 8 + q];
        uint2 v3 = X2[(size_t)c4.w * 8 + q];
        add4h(a, v0);
        add4h(a, v1);
        add4h(a, v2);
        add4h(a, v3);
    }
    float iw = inv[w];
    float h[4];
#pragma unroll
    for (int j = 0; j < 4; ++j) h[j] = fmaxf(iw * a[j] + bb[j], 0.0f);
    // hws[w][2q],[2q+1] = iw * sum_k h[k] * W2[k][c]
    float s0 = 0.0f, s1 = 0.0f;
#pragma unroll
    for (int qq = 0; qq < 8; ++qq) {
#pragma unroll
        for (int j = 0; j < 4; ++j) {
            float hv = __shfl(h[j], grpbase + qq);
            float2 wv = *(const float2*)&W2s[(4 * qq + j) * 16 + 2 * q];
            s0 = fmaf(hv, wv.x, s0);
            s1 = fmaf(hv, wv.y, s1);
        }
    }
    hws[(size_t)w * 8 + q] = __floats2half2_rn(s0 * iw, s1 * iw);
}

// Layer 2: one node per 8-lane group; lane owns 2 cols (half2 of the 32 B row).
__global__ __launch_bounds__(256) void k_agg2(const int* __restrict__ rpbeg,
                                              const int* __restrict__ rpcnt,
                                              const int* __restrict__ col,
                                              const unsigned* __restrict__ H,
                                              const float* __restrict__ inv,
                                              const float* __restrict__ b2,
                                              unsigned* __restrict__ z, int n) {
    int t = threadIdx.x;
    int w = (blockIdx.x * 256 + t) >> 3;
    if (w >= n) return;
    int q = t & 7;
    float bb0 = b2[2 * q], bb1 = b2[2 * q + 1];
    int beg = rpbeg[w], endp = beg + rpcnt[w];
    float a[2] = {};
    add2h(a, H[(size_t)w * 8 + q]);  // self-loop
    for (int i = beg; i < endp; i += 4) {
        int4 c4 = *(const int4*)(col + i);
        unsigned v0 = H[(size_t)c4.x * 8 + q];
        unsigned v1 = H[(size_t)c4.y * 8 + q];
        unsigned v2 = H[(size_t)c4.z * 8 + q];
        unsigned v3 = H[(size_t)c4.w * 8 + q];
        add2h(a, v0);
        add2h(a, v1);
        add2h(a, v2);
        add2h(a, v3);
    }
    float iw = inv[w];
    __half2 r = __floats2half2_rn(iw * a[0] + bb0, iw * a[1] + bb1);
    z[(size_t)w * 8 + q] = *(unsigned*)&r;
}

__device__ __forceinline__ float dot8h(uint4 u, uint4 v, float s) {
    const __half2* pu = (const __half2*)&u;
    const __half2* pv = (const __half2*)&v;
#pragma unroll
    for (int i = 0; i < 4; ++i) {
#if __has_builtin(__builtin_amdgcn_fdot2)
        s = __builtin_amdgcn_fdot2(pu[i], pv[i], s, false);
#else
        float2 a = __half22float2(pu[i]);
        float2 b = __half22float2(pv[i]);
        s += a.x * b.x + a.y * b.y;
#endif
    }
    return s;
}

__global__ void k_decode(const int* __restrict__ eli, const uint4* __restrict__ z4,
                         float* __restrict__ out, int L) {
    int e = blockIdx.x * blockDim.x + threadIdx.x;
    if (e >= L) return;
    int a = eli[e], b = eli[L + e];
    uint4 ua0 = z4[(size_t)a * 2], ua1 = z4[(size_t)a * 2 + 1];
    uint4 ub0 = z4[(size_t)b * 2], ub1 = z4[(size_t)b * 2 + 1];
    out[e] = dot8h(ua1, ub1, dot8h(ua0, ub0, 0.0f));
}

extern "C" void kernel_launch(void* const* d_in, const int* in_sizes, int n_in,
                              void* d_out, int out_size, void* d_ws, size_t ws_size,
                              hipStream_t stream) {
    const float* x   = (const float*)d_in[0];
    const int*   ei  = (const int*)d_in[1];
    const int*   eli = (const int*)d_in[2];
    const float* W1  = (const float*)d_in[3];
    const float* b1  = (const float*)d_in[4];
    const float* W2  = (const float*)d_in[5];
    const float* b2  = (const float*)d_in[6];
    float* out = (float*)d_out;

    int n = in_sizes[0] / 128;
    int E = in_sizes[1] / 2;
    int L = in_sizes[2] / 2;
    const int* src = ei;
    const int* dst = ei + E;
    int NB = (n + NPB - 1) / NPB;  // 782 for n=100k (packing needs n <= 131072)

    // ws: X (n+1)x8 uint2 | hws (n+1)x8 half2 | z n x 8 half2 | inv n f |
    //     rpbeg n | rpcnt n | eb E | col E+400*NB | bcnt NB | bbase NB+1 |
    //     pbase NB+1 | bcursor NB
    uint2* X       = (uint2*)d_ws;
    unsigned* hws  = (unsigned*)(X + (size_t)(n + 1) * 8);
    unsigned* z    = hws + (size_t)(n + 1) * 8;
    float* inv     = (float*)(z + (size_t)n * 8);
    int* rpbeg     = (int*)(inv + n);
    int* rpcnt     = rpbeg + n;
    unsigned* eb   = (unsigned*)(rpcnt + n);
    int* col       = (int*)(eb + E);
    int* bcnt      = col + E + 400 * NB;
    int* bbase     = bcnt + NB;
    int* pbase     = bbase + NB + 1;
    int* bcursor   = pbase + NB + 1;

    hipMemsetAsync(bcnt, 0, NB * sizeof(int), stream);
    k_a1<<<512, 256, 0, stream>>>(dst, bcnt, E, NB);
    k_scanb<<<1, 256, 0, stream>>>(bcnt, bbase, bcursor, pbase, NB);
    k_a3<<<(E + A3_CHUNK - 1) / A3_CHUNK, 256, 0, stream>>>(src, dst, bcursor, eb, E, NB);
    k_csr<<<NB, 256, 0, stream>>>(bbase, pbase, eb, col, rpbeg, rpcnt, inv, n, NB);
    k_xw<<<(n + 127) / 128, 256, 0, stream>>>(x, W1, inv, X, hws, n);
    k_agg1<<<((size_t)n * 8 + 255) / 256, 256, 0, stream>>>(rpbeg, rpcnt, col, X, inv, b1, W2, (__half2*)hws, n);
    k_agg2<<<((size_t)n * 8 + 255) / 256, 256, 0, stream>>>(rpbeg, rpcnt, col, hws, inv, b2, z, n);
    k_decode<<<(L + 255) / 256, 256, 0, stream>>>(eli, (const uint4*)z, out, L);
}